// Round 1
// 1022.653 us; speedup vs baseline: 1.2231x; 1.2231x over previous
//
#include <hip/hip_runtime.h>
#include <hip/hip_bf16.h>
#include <hip/hip_fp16.h>
#include <hip/hip_fp8.h>

#define NFEAT 512
#define HID   64
#define NCLS  40

typedef short bf16x8 __attribute__((ext_vector_type(8)));
typedef float f32x4  __attribute__((ext_vector_type(4)));
typedef float v2f    __attribute__((ext_vector_type(2)));

__device__ inline short bfs(float f) {
  __hip_bfloat16 h = __float2bfloat16(f);
  return __builtin_bit_cast(short, h);
}
__device__ inline int pk(float a, float b) {  // two bf16 packed, a = low half
  return (int)(unsigned short)bfs(a) | ((int)(unsigned short)bfs(b) << 16);
}

// ---- fp8 e4m3 (OCP) pack/unpack: 8 fp8 <-> int2 ----
__device__ inline void up8f8(const int2 v, float f[8]) {
#if __has_builtin(__builtin_amdgcn_cvt_pk_f32_fp8)
  v2f p;
  p = __builtin_amdgcn_cvt_pk_f32_fp8(v.x, false); f[0] = p[0]; f[1] = p[1];
  p = __builtin_amdgcn_cvt_pk_f32_fp8(v.x, true);  f[2] = p[0]; f[3] = p[1];
  p = __builtin_amdgcn_cvt_pk_f32_fp8(v.y, false); f[4] = p[0]; f[5] = p[1];
  p = __builtin_amdgcn_cvt_pk_f32_fp8(v.y, true);  f[6] = p[0]; f[7] = p[1];
#else
  const unsigned char* b = (const unsigned char*)&v;
  #pragma unroll
  for (int i = 0; i < 8; ++i) { __hip_fp8_e4m3 h; h.__x = b[i]; f[i] = (float)h; }
#endif
}
__device__ inline int2 pk8f8(const float f[8]) {
#if __has_builtin(__builtin_amdgcn_cvt_pk_fp8_f32)
  int lo = 0, hi = 0;
  lo = __builtin_amdgcn_cvt_pk_fp8_f32(f[0], f[1], lo, false);
  lo = __builtin_amdgcn_cvt_pk_fp8_f32(f[2], f[3], lo, true);
  hi = __builtin_amdgcn_cvt_pk_fp8_f32(f[4], f[5], hi, false);
  hi = __builtin_amdgcn_cvt_pk_fp8_f32(f[6], f[7], hi, true);
  return make_int2(lo, hi);
#else
  int2 r; unsigned char* b = (unsigned char*)&r;
  #pragma unroll
  for (int i = 0; i < 8; ++i) { __hip_fp8_e4m3 h((float)f[i]); b[i] = h.__x; }
  return r;
#endif
}
__device__ inline unsigned char f8b(float v) {
#if __has_builtin(__builtin_amdgcn_cvt_pk_fp8_f32)
  int r = __builtin_amdgcn_cvt_pk_fp8_f32(v, v, 0, false);
  return (unsigned char)(r & 0xff);
#else
  __hip_fp8_e4m3 h(v); return h.__x;
#endif
}

// ---------------- degree / dinv ----------------

static __global__ void deg_i_kernel(const int* __restrict__ dst, int* __restrict__ deg, int E) {
  int e = blockIdx.x * blockDim.x + threadIdx.x;
  if (e < E) atomicAdd(&deg[dst[e]], 1);
}

static __global__ void dinv_kernel(const int* __restrict__ deg, float* __restrict__ dinv, int N) {
  int i = blockIdx.x * blockDim.x + threadIdx.x;
  if (i < N) dinv[i] = rsqrtf((float)deg[i] + 1.0f);
}

// ---------------- weight preconversion to bf16 ----------------
static __global__ void w1conv_kernel(const float* __restrict__ w1, short* __restrict__ w1bf) {
  int t = blockIdx.x * blockDim.x + threadIdx.x;  // 32768
  if (t >= NFEAT * HID) return;
  int k = t >> 6, n = t & 63;
  w1bf[n * NFEAT + k] = bfs(w1[k * HID + n]);
}
static __global__ void w2conv_kernel(const float* __restrict__ w2, short* __restrict__ w2bf) {
  int t = blockIdx.x * blockDim.x + threadIdx.x;  // 3072
  if (t >= 48 * HID) return;
  int n = t >> 6, k = t & 63;
  w2bf[t] = (n < NCLS) ? bfs(w2[k * NCLS + n]) : (short)0;
}

// ---------------- MFMA MLP ----------------
// Block: 256 threads (4 waves), 64 rows. Writes y0 = dinv*h as fp8 (64 B row stride)
// and out = g0*h (f32).
static __global__ __launch_bounds__(256) void mlp_mfma_kernel(
    const float* __restrict__ x, const short* __restrict__ w1bf, const float* __restrict__ b1,
    const short* __restrict__ w2bf, const float* __restrict__ b2, const float* __restrict__ temp,
    const float* __restrict__ dinv, unsigned char* __restrict__ cur, float* __restrict__ out, int N)
{
  __shared__ __align__(16) short Al[64][72];
  __shared__ __align__(16) short Bl[64][72];
  __shared__ __align__(16) short Hl[64][72];
  __shared__ __align__(16) short W2l[48][72];
  const int tid = threadIdx.x;
  const int w = tid >> 6, lane = tid & 63;
  const int q = lane >> 4, m = lane & 15;
  const long row0 = (long)blockIdx.x * 64;

  if (tid < 192) {
    int n = tid >> 2, ch = tid & 3;
    const int4* sp = (const int4*)(w2bf + n * 64 + ch * 16);
    *(int4*)&W2l[n][ch * 16]     = sp[0];
    *(int4*)&W2l[n][ch * 16 + 8] = sp[1];
  }

  f32x4 zf = {0.f, 0.f, 0.f, 0.f};
  f32x4 acc[4] = {zf, zf, zf, zf};

  const int ar = tid >> 2, ch = tid & 3;
  const long gr = row0 + ar;

  for (int kk = 0; kk < NFEAT; kk += 64) {
    float4 v0, v1, v2, v3;
    if (gr < N) {
      const float4* xp = (const float4*)(x + gr * NFEAT + kk + ch * 16);
      v0 = xp[0]; v1 = xp[1]; v2 = xp[2]; v3 = xp[3];
    } else {
      v0 = v1 = v2 = v3 = make_float4(0.f, 0.f, 0.f, 0.f);
    }
    const int4* bp = (const int4*)(w1bf + ar * NFEAT + kk + ch * 16);
    int4 bv0 = bp[0], bv1 = bp[1];

    __syncthreads();
    int4 a0 = make_int4(pk(v0.x, v0.y), pk(v0.z, v0.w), pk(v1.x, v1.y), pk(v1.z, v1.w));
    int4 a1 = make_int4(pk(v2.x, v2.y), pk(v2.z, v2.w), pk(v3.x, v3.y), pk(v3.z, v3.w));
    *(int4*)&Al[ar][ch * 16]     = a0;
    *(int4*)&Al[ar][ch * 16 + 8] = a1;
    *(int4*)&Bl[ar][ch * 16]     = bv0;
    *(int4*)&Bl[ar][ch * 16 + 8] = bv1;
    __syncthreads();

    #pragma unroll
    for (int s = 0; s < 2; ++s) {
      bf16x8 a = *(const bf16x8*)&Al[w * 16 + m][s * 32 + q * 8];
      #pragma unroll
      for (int c = 0; c < 4; ++c) {
        bf16x8 b = *(const bf16x8*)&Bl[c * 16 + m][s * 32 + q * 8];
        acc[c] = __builtin_amdgcn_mfma_f32_16x16x32_bf16(a, b, acc[c], 0, 0, 0);
      }
    }
  }

  #pragma unroll
  for (int c = 0; c < 4; ++c) {
    int col = c * 16 + m;
    float bb = b1[col];
    #pragma unroll
    for (int r = 0; r < 4; ++r) {
      int rl = w * 16 + q * 4 + r;
      Hl[rl][col] = bfs(fmaxf(acc[c][r] + bb, 0.0f));
    }
  }
  __syncthreads();

  f32x4 acc2[3] = {zf, zf, zf};
  #pragma unroll
  for (int s = 0; s < 2; ++s) {
    bf16x8 a = *(const bf16x8*)&Hl[w * 16 + m][s * 32 + q * 8];
    #pragma unroll
    for (int c = 0; c < 3; ++c) {
      bf16x8 b = *(const bf16x8*)&W2l[c * 16 + m][s * 32 + q * 8];
      acc2[c] = __builtin_amdgcn_mfma_f32_16x16x32_bf16(a, b, acc2[c], 0, 0, 0);
    }
  }

  float g0 = fmaxf(temp[0], 0.0f);
  #pragma unroll
  for (int c = 0; c < 3; ++c) {
    int col = c * 16 + m;
    if (col < NCLS) {
      float bb = b2[col];
      #pragma unroll
      for (int r = 0; r < 4; ++r) {
        long grow = row0 + w * 16 + q * 4 + r;
        if (grow < N) {
          float vv = acc2[c][r] + bb;
          cur[grow * 64 + col] = f8b(dinv[grow] * vv);  // y0 = dinv*h, fp8
          out[grow * NCLS + col] = g0 * vv;
        }
      }
    }
  }
}

// ---------------- multi-block exclusive scan of deg -> rowptr/cursor ----------------

static __global__ __launch_bounds__(256) void scan1_kernel(const int* __restrict__ deg,
                                                           int* __restrict__ bsum, int N) {
  __shared__ int s[256];
  int tid = threadIdx.x;
  int i = blockIdx.x * 256 + tid;
  s[tid] = (i < N) ? deg[i] : 0;
  __syncthreads();
  for (int off = 128; off > 0; off >>= 1) {
    if (tid < off) s[tid] += s[tid + off];
    __syncthreads();
  }
  if (tid == 0) bsum[blockIdx.x] = s[0];
}

static __global__ __launch_bounds__(512) void scan2_kernel(int* __restrict__ bsum,
                                                           int* __restrict__ total, int nb) {
  __shared__ int s[512];
  int tid = threadIdx.x;
  int v = (tid < nb) ? bsum[tid] : 0;
  s[tid] = v;
  __syncthreads();
  for (int off = 1; off < 512; off <<= 1) {
    int t = (tid >= off) ? s[tid - off] : 0;
    __syncthreads();
    s[tid] += t;
    __syncthreads();
  }
  if (tid < nb) bsum[tid] = s[tid] - v;
  if (tid == 511) *total = s[511];
}

static __global__ __launch_bounds__(256) void scan3_kernel(const int* __restrict__ deg,
                                                           const int* __restrict__ bsum,
                                                           const int* __restrict__ total,
                                                           int* __restrict__ rowptr,
                                                           int* __restrict__ cursor, int N) {
  __shared__ int s[256];
  int tid = threadIdx.x;
  int i = blockIdx.x * 256 + tid;
  int v = (i < N) ? deg[i] : 0;
  s[tid] = v;
  __syncthreads();
  for (int off = 1; off < 256; off <<= 1) {
    int t = (tid >= off) ? s[tid - off] : 0;
    __syncthreads();
    s[tid] += t;
    __syncthreads();
  }
  if (i < N) {
    int e = bsum[blockIdx.x] + s[tid] - v;
    rowptr[i] = e;
    cursor[i] = e;
  }
  if (i == N) rowptr[N] = *total;
}

// ---------------- CSR build: bucketed counting sort ----------------
// Old atomic-scatter fill hit a ~300 us floor: 3.2M random 4 B stores -> 16x
// write amplification (WRITE_SIZE 194 MB vs 12.8 MB payload, counters r0).
// New scheme keeps all fine-grained scatter in LDS; every HBM write is a
// contiguous run.
//   Buckets = 256-node ranges; bucket b's CSR region IS [rowptr[256b], rowptr[256(b+1)])
//   pass1 (fill_bin): per-block LDS histogram+scan, ONE global atomic per
//     bucket per block to reserve space, write edges grouped by bucket as
//     packed (src | (dst&255)<<17) into the csr buffer itself (src < 2^17).
//   pass2 (fill_scatter): one block per bucket; LDS scatter to CSR order via
//     per-node LDS cursors, coalesced rewrite in place.

#define FB_EPT 16
#define FB_EPB (256 * FB_EPT)   // 4096 edges/block
#define FB_NBMAX 512            // supports N <= 131072
#define FS_CAP 12288            // bucket capacity (uniform input: ~8200 +- 90)

static __global__ void binit_kernel(const int* __restrict__ rowptr, int* __restrict__ bcur, int NB) {
  int b = blockIdx.x * blockDim.x + threadIdx.x;
  if (b < NB) bcur[b] = rowptr[b << 8];
}

static __global__ __launch_bounds__(256) void fill_bin_kernel(
    const int* __restrict__ src, const int* __restrict__ dst,
    int* __restrict__ bcur, int* __restrict__ csr, int E, int NB)
{
  __shared__ int cnt[FB_NBMAX];
  __shared__ int pfx[FB_NBMAX];
  __shared__ int gbase[FB_NBMAX];
  __shared__ int stg[FB_EPB];
  __shared__ unsigned short bmap[FB_EPB];
  const int tid = threadIdx.x;
  const int e0 = blockIdx.x * FB_EPB;

  cnt[tid] = 0; cnt[tid + 256] = 0;
  __syncthreads();

  int pk_[FB_EPT], b_[FB_EPT], r_[FB_EPT];
  #pragma unroll
  for (int j = 0; j < FB_EPT; ++j) {
    int e = e0 + j * 256 + tid;  // coalesced
    if (e < E) {
      int s = src[e], d = dst[e];
      pk_[j] = s | ((d & 255) << 17);
      b_[j] = d >> 8;
      r_[j] = atomicAdd(&cnt[b_[j]], 1);
    } else b_[j] = -1;
  }
  __syncthreads();

  // inclusive Hillis-Steele scan of cnt into pfx (512 entries, 2/thread)
  pfx[tid] = cnt[tid]; pfx[tid + 256] = cnt[tid + 256];
  __syncthreads();
  for (int off = 1; off < FB_NBMAX; off <<= 1) {
    int a = (tid >= off) ? pfx[tid - off] : 0;
    int b = (tid + 256 >= off) ? pfx[tid + 256 - off] : 0;
    __syncthreads();
    pfx[tid] += a; pfx[tid + 256] += b;
    __syncthreads();
  }

  // reserve global space: one atomic per non-empty bucket
  {
    int b0 = tid, b1 = tid + 256;
    if (b0 < NB && cnt[b0]) gbase[b0] = atomicAdd(&bcur[b0], cnt[b0]);
    if (b1 < NB && cnt[b1]) gbase[b1] = atomicAdd(&bcur[b1], cnt[b1]);
  }
  __syncthreads();

  // place into LDS staging grouped by bucket
  #pragma unroll
  for (int j = 0; j < FB_EPT; ++j) {
    if (b_[j] >= 0) {
      int slot = pfx[b_[j]] - cnt[b_[j]] + r_[j];
      stg[slot] = pk_[j];
      bmap[slot] = (unsigned short)b_[j];
    }
  }
  __syncthreads();

  // copy out: consecutive slots -> consecutive global addresses within a run
  const int total = pfx[FB_NBMAX - 1];
  for (int slot = tid; slot < total; slot += 256) {
    int b = bmap[slot];
    int local = slot - (pfx[b] - cnt[b]);
    csr[gbase[b] + local] = stg[slot];
  }
}

static __global__ __launch_bounds__(256) void fill_scatter_kernel(
    const int* __restrict__ rowptr, int* __restrict__ csr,
    const int* __restrict__ src, const int* __restrict__ dst,
    int* __restrict__ cursor, int N, int E)
{
  __shared__ int curl[256];
  __shared__ int buf[FS_CAP];
  const int tid = threadIdx.x;
  const int node0 = blockIdx.x << 8;
  const int node1 = min(node0 + 256, N);
  const int beg = rowptr[node0], end = rowptr[node1];
  const int cnt = end - beg;

  if (cnt <= FS_CAP) {
    int nd = node0 + tid;
    curl[tid] = (nd < node1) ? rowptr[nd] - beg : 0;
    __syncthreads();
    for (int e = beg + tid; e < end; e += 256) {
      int p = csr[e];
      int ld = (p >> 17) & 255;
      int pos = atomicAdd(&curl[ld], 1);
      buf[pos] = p & 0x1FFFF;
    }
    __syncthreads();
    for (int i = tid; i < cnt; i += 256) csr[beg + i] = buf[i];
  } else {
    // overflow safety net (P~0 for uniform input): rebuild this bucket from
    // the raw edge list via per-node global cursors (init'd = rowptr by scan3).
    for (int e = tid; e < E; e += 256) {
      int d = dst[e];
      if ((d >> 8) == blockIdx.x) {
        int pos = atomicAdd(&cursor[d], 1);
        csr[pos] = src[e];
      }
    }
  }
}

// ---------------- legacy atomic-scatter fill (fallback when NB > FB_NBMAX) ---

static __global__ void fill_kernel(const int* __restrict__ src, const int* __restrict__ dst,
                                   int* __restrict__ cursor, int* __restrict__ csr, int E) {
  int e = blockIdx.x * blockDim.x + threadIdx.x;
  if (e >= E) return;
  int s = src[e], d = dst[e];
  int pos = atomicAdd(&cursor[d], 1);
  csr[pos] = s;
}

// ---------------- fused propagation step (CSR gather, y-form, fp8, unroll-8) ----------
// cur rows: 40 fp8 bytes padded to 64 B stride -> exactly ONE cache line per edge.
// y' = dinv^2 * (y[row] + sum y[src]);  out += gamma*dinv*(y[row] + sum y[src])

static __global__ __launch_bounds__(256) void gather_kernel(
    const int* __restrict__ rowptr, const int* __restrict__ csr,
    const float* __restrict__ dinv, const float* __restrict__ temp, int k,
    const unsigned char* __restrict__ cur, unsigned char* __restrict__ nxt,
    float4* __restrict__ out, int n5)
{
  int t = blockIdx.x * blockDim.x + threadIdx.x;
  if (t >= n5) return;
  int row = t / 5, c4 = t - row * 5;
  int c8 = c4 * 8;
  int beg = rowptr[row], end = rowptr[row + 1];
  float dv = dinv[row];

  float a[8];
  up8f8(*(const int2*)(cur + (row << 6) + c8), a);   // self term y[row]

  int e = beg;
  // unroll-8: phase-separated (8 idx loads -> 8 gathers -> accumulate)
  for (; e + 7 < end; e += 8) {
    int idx[8];
    #pragma unroll
    for (int j = 0; j < 8; ++j) idx[j] = __builtin_nontemporal_load(csr + e + j);
    int2 g[8];
    #pragma unroll
    for (int j = 0; j < 8; ++j) g[j] = *(const int2*)(cur + ((long)idx[j] << 6) + c8);
    #pragma unroll
    for (int j = 0; j < 8; ++j) {
      float u[8];
      up8f8(g[j], u);
      #pragma unroll
      for (int i = 0; i < 8; ++i) a[i] += u[i];
    }
  }
  for (; e + 1 < end; e += 2) {
    int i0 = __builtin_nontemporal_load(csr + e);
    int i1 = __builtin_nontemporal_load(csr + e + 1);
    int2 g0 = *(const int2*)(cur + ((long)i0 << 6) + c8);
    int2 g1 = *(const int2*)(cur + ((long)i1 << 6) + c8);
    float u0[8], u1[8];
    up8f8(g0, u0); up8f8(g1, u1);
    #pragma unroll
    for (int i = 0; i < 8; ++i) a[i] += u0[i] + u1[i];
  }
  if (e < end) {
    int i0 = __builtin_nontemporal_load(csr + e);
    float u0[8];
    up8f8(*(const int2*)(cur + ((long)i0 << 6) + c8), u0);
    #pragma unroll
    for (int i = 0; i < 8; ++i) a[i] += u0[i];
  }

  float d2 = dv * dv;
  float y[8];
  #pragma unroll
  for (int i = 0; i < 8; ++i) y[i] = d2 * a[i];
  *(int2*)(nxt + (row << 6) + c8) = pk8f8(y);

  float gd = fmaxf(temp[k], 0.0f) * dv;   // gamma * dinv
  int oi = row * 10 + c4 * 2;
  float4 o0 = out[oi], o1 = out[oi + 1];
  out[oi]     = make_float4(fmaf(gd, a[0], o0.x), fmaf(gd, a[1], o0.y), fmaf(gd, a[2], o0.z), fmaf(gd, a[3], o0.w));
  out[oi + 1] = make_float4(fmaf(gd, a[4], o1.x), fmaf(gd, a[5], o1.y), fmaf(gd, a[6], o1.z), fmaf(gd, a[7], o1.w));
}

// ---------------- fallback scatter path (only if ws too small) ----------------

static __global__ void selfloop_kernel(const float* __restrict__ dinv, const float4* __restrict__ cur,
                                       float4* __restrict__ nxt, int n10) {
  int t = blockIdx.x * blockDim.x + threadIdx.x;
  if (t >= n10) return;
  int i = t / 10;
  float dv = dinv[i], s = dv * dv;
  float4 v = cur[t];
  nxt[t] = make_float4(s * v.x, s * v.y, s * v.z, s * v.w);
}

static __global__ void scatter_kernel(const int* __restrict__ src, const int* __restrict__ dst,
                                      const float* __restrict__ dinv,
                                      const float4* __restrict__ cur, float* __restrict__ nxt, int items) {
  int t = blockIdx.x * blockDim.x + threadIdx.x;
  if (t >= items) return;
  int e = t / 10, c4 = t - e * 10;
  int s = src[e], d = dst[e];
  float nm = dinv[s] * dinv[d];
  float4 v = cur[s * 10 + c4];
  float* np = nxt + (size_t)d * NCLS + c4 * 4;
  unsafeAtomicAdd(np + 0, nm * v.x);
  unsafeAtomicAdd(np + 1, nm * v.y);
  unsafeAtomicAdd(np + 2, nm * v.z);
  unsafeAtomicAdd(np + 3, nm * v.w);
}

static __global__ void axpy_kernel(const float* __restrict__ temp, int k,
                                   const float4* __restrict__ nxt, float4* __restrict__ out, int n10) {
  int t = blockIdx.x * blockDim.x + threadIdx.x;
  if (t >= n10) return;
  float g = fmaxf(temp[k], 0.0f);
  float4 v = nxt[t], o = out[t];
  out[t] = make_float4(o.x + g * v.x, o.y + g * v.y, o.z + g * v.z, o.w + g * v.w);
}

static __global__ __launch_bounds__(256) void mlp_kernel(
    const float* __restrict__ x, const float* __restrict__ w1, const float* __restrict__ b1,
    const float* __restrict__ w2, const float* __restrict__ b2, const float* __restrict__ temp,
    float* __restrict__ cur, float* __restrict__ out, int N)
{
  __shared__ __align__(16) float xs[4][NFEAT];
  __shared__ float hs[4][HID];
  const int w = threadIdx.x >> 6, lane = threadIdx.x & 63;
  const int i = blockIdx.x * 4 + w;
  if (i < N) {
    const float4* xrow = (const float4*)(x + (size_t)i * NFEAT);
    float4* xsr = (float4*)xs[w];
    xsr[lane]      = xrow[lane];
    xsr[lane + 64] = xrow[lane + 64];
  }
  __syncthreads();
  if (i < N) {
    float acc = b1[lane];
    #pragma unroll 8
    for (int k = 0; k < NFEAT; ++k)
      acc = fmaf(xs[w][k], w1[k * HID + lane], acc);
    hs[w][lane] = fmaxf(acc, 0.0f);
  }
  __syncthreads();
  if (i < N && lane < NCLS) {
    float a2 = b2[lane];
    #pragma unroll
    for (int j = 0; j < HID; ++j)
      a2 = fmaf(hs[w][j], w2[j * NCLS + lane], a2);
    float g0 = fmaxf(temp[0], 0.0f);
    cur[(size_t)i * NCLS + lane] = a2;
    out[(size_t)i * NCLS + lane] = g0 * a2;
  }
}

// ---------------- log_softmax ----------------
static __global__ void logsoftmax_kernel(float* __restrict__ out, int N) {
  int i = blockIdx.x * blockDim.x + threadIdx.x;
  if (i >= N) return;
  float4* row = (float4*)(out + (size_t)i * NCLS);
  float4 v[10];
  float m = -3.4e38f;
  #pragma unroll
  for (int r = 0; r < 10; ++r) {
    v[r] = row[r];
    m = fmaxf(m, fmaxf(fmaxf(v[r].x, v[r].y), fmaxf(v[r].z, v[r].w)));
  }
  float sum = 0.0f;
  #pragma unroll
  for (int r = 0; r < 10; ++r)
    sum += __expf(v[r].x - m) + __expf(v[r].y - m) + __expf(v[r].z - m) + __expf(v[r].w - m);
  float l = m + __logf(sum);
  #pragma unroll
  for (int r = 0; r < 10; ++r)
    row[r] = make_float4(v[r].x - l, v[r].y - l, v[r].z - l, v[r].w - l);
}

// ---------------- launch ----------------

extern "C" void kernel_launch(void* const* d_in, const int* in_sizes, int n_in,
                              void* d_out, int out_size, void* d_ws, size_t ws_size,
                              hipStream_t stream) {
  const float* x    = (const float*)d_in[0];
  const int*   ei   = (const int*)d_in[1];
  const float* w1   = (const float*)d_in[2];
  const float* b1   = (const float*)d_in[3];
  const float* w2   = (const float*)d_in[4];
  const float* b2   = (const float*)d_in[5];
  const float* temp = (const float*)d_in[6];

  const int N = in_sizes[0] / NFEAT;   // 100000
  const int E = in_sizes[1] / 2;       // 3200000
  const int* src = ei;
  const int* dst = ei + E;
  float* out = (float*)d_out;

  char* ws = (char*)d_ws;
  size_t off = 0;
  auto alloc = [&](size_t bytes) { size_t o = off; off += (bytes + 255) & ~(size_t)255; return o; };
  float* dinv   = (float*)(ws + alloc((size_t)N * 4));
  int*   deg    = (int*)  (ws + alloc((size_t)N * 4));
  unsigned char* curA = (unsigned char*)(ws + alloc((size_t)N * 64));  // fp8, 64 B rows
  unsigned char* curB = (unsigned char*)(ws + alloc((size_t)N * 64));
  int*   rowptr = (int*)  (ws + alloc((size_t)(N + 1) * 4));
  int*   cursor = (int*)  (ws + alloc((size_t)N * 4));
  int*   bsum   = (int*)  (ws + alloc(1024 * 4));
  int*   total  = (int*)  (ws + alloc(256));
  int*   bcur   = (int*)  (ws + alloc(FB_NBMAX * 4));
  short* w1bf   = (short*)(ws + alloc((size_t)NFEAT * HID * 2));
  short* w2bf   = (short*)(ws + alloc((size_t)48 * HID * 2));
  int*   csr    = (int*)  (ws + alloc((size_t)E * 4));
  // fallback needs f32 cur buffers
  float* fA     = (float*)curA;
  const bool csr_ok = (off <= ws_size);

  hipMemsetAsync(deg, 0, (size_t)N * sizeof(int), stream);
  deg_i_kernel<<<(E + 255) / 256, 256, 0, stream>>>(dst, deg, E);
  dinv_kernel<<<(N + 255) / 256, 256, 0, stream>>>(deg, dinv, N);

  if (csr_ok) {
    w1conv_kernel<<<(NFEAT * HID + 255) / 256, 256, 0, stream>>>(w1, w1bf);
    w2conv_kernel<<<(48 * HID + 255) / 256, 256, 0, stream>>>(w2, w2bf);
    mlp_mfma_kernel<<<(N + 63) / 64, 256, 0, stream>>>(x, w1bf, b1, w2bf, b2, temp, dinv,
                                                       curA, out, N);

    const int nb = (N + 255) / 256;
    scan1_kernel<<<nb, 256, 0, stream>>>(deg, bsum, N);
    scan2_kernel<<<1, 512, 0, stream>>>(bsum, total, nb);
    scan3_kernel<<<(N + 256) / 256, 256, 0, stream>>>(deg, bsum, total, rowptr, cursor, N);

    const int NB = (N + 255) >> 8;  // 256-node buckets
    if (NB <= FB_NBMAX && N <= (1 << 17)) {
      binit_kernel<<<(NB + 255) / 256, 256, 0, stream>>>(rowptr, bcur, NB);
      fill_bin_kernel<<<(E + FB_EPB - 1) / FB_EPB, 256, 0, stream>>>(src, dst, bcur, csr, E, NB);
      fill_scatter_kernel<<<NB, 256, 0, stream>>>(rowptr, csr, src, dst, cursor, N, E);
    } else {
      fill_kernel<<<(E + 255) / 256, 256, 0, stream>>>(src, dst, cursor, csr, E);
    }

    const int n5 = N * 5;
    unsigned char* cur = curA;
    unsigned char* nxt = curB;
    for (int k = 0; k < 10; ++k) {
      gather_kernel<<<(n5 + 255) / 256, 256, 0, stream>>>(
          rowptr, csr, dinv, temp, k + 1, cur, nxt, (float4*)out, n5);
      unsigned char* t2 = cur; cur = nxt; nxt = t2;
    }
  } else {
    // f32 fallback (uses curA region as float storage; requires less ws than main path)
    float* fB = (float*)curB;
    mlp_kernel<<<(N + 3) / 4, 256, 0, stream>>>(x, w1, b1, w2, b2, temp, fA, out, N);
    const int n10 = N * 10;
    const int items = E * 10;
    float* cur = fA;
    float* nxt = fB;
    for (int k = 0; k < 10; ++k) {
      selfloop_kernel<<<(n10 + 255) / 256, 256, 0, stream>>>(dinv, (const float4*)cur, (float4*)nxt, n10);
      scatter_kernel<<<(items + 255) / 256, 256, 0, stream>>>(src, dst, dinv, (const float4*)cur, nxt, items);
      axpy_kernel<<<(n10 + 255) / 256, 256, 0, stream>>>(temp, k + 1, (const float4*)nxt, (float4*)out, n10);
      float* t2 = cur; cur = nxt; nxt = t2;
    }
  }

  logsoftmax_kernel<<<(N + 255) / 256, 256, 0, stream>>>(out, N);
}

// Round 2
// 918.270 us; speedup vs baseline: 1.3621x; 1.1137x over previous
//
#include <hip/hip_runtime.h>
#include <hip/hip_bf16.h>
#include <hip/hip_fp16.h>
#include <hip/hip_fp8.h>

#define NFEAT 512
#define HID   64
#define NCLS  40

typedef short bf16x8 __attribute__((ext_vector_type(8)));
typedef float f32x4  __attribute__((ext_vector_type(4)));
typedef float v2f    __attribute__((ext_vector_type(2)));

__device__ inline short bfs(float f) {
  __hip_bfloat16 h = __float2bfloat16(f);
  return __builtin_bit_cast(short, h);
}
__device__ inline int pk(float a, float b) {  // two bf16 packed, a = low half
  return (int)(unsigned short)bfs(a) | ((int)(unsigned short)bfs(b) << 16);
}

// ---- fp8 e4m3 (OCP) pack/unpack: 8 fp8 <-> int2 ----
__device__ inline void up8f8(const int2 v, float f[8]) {
#if __has_builtin(__builtin_amdgcn_cvt_pk_f32_fp8)
  v2f p;
  p = __builtin_amdgcn_cvt_pk_f32_fp8(v.x, false); f[0] = p[0]; f[1] = p[1];
  p = __builtin_amdgcn_cvt_pk_f32_fp8(v.x, true);  f[2] = p[0]; f[3] = p[1];
  p = __builtin_amdgcn_cvt_pk_f32_fp8(v.y, false); f[4] = p[0]; f[5] = p[1];
  p = __builtin_amdgcn_cvt_pk_f32_fp8(v.y, true);  f[6] = p[0]; f[7] = p[1];
#else
  const unsigned char* b = (const unsigned char*)&v;
  #pragma unroll
  for (int i = 0; i < 8; ++i) { __hip_fp8_e4m3 h; h.__x = b[i]; f[i] = (float)h; }
#endif
}
__device__ inline int2 pk8f8(const float f[8]) {
#if __has_builtin(__builtin_amdgcn_cvt_pk_fp8_f32)
  int lo = 0, hi = 0;
  lo = __builtin_amdgcn_cvt_pk_fp8_f32(f[0], f[1], lo, false);
  lo = __builtin_amdgcn_cvt_pk_fp8_f32(f[2], f[3], lo, true);
  hi = __builtin_amdgcn_cvt_pk_fp8_f32(f[4], f[5], hi, false);
  hi = __builtin_amdgcn_cvt_pk_fp8_f32(f[6], f[7], hi, true);
  return make_int2(lo, hi);
#else
  int2 r; unsigned char* b = (unsigned char*)&r;
  #pragma unroll
  for (int i = 0; i < 8; ++i) { __hip_fp8_e4m3 h((float)f[i]); b[i] = h.__x; }
  return r;
#endif
}
__device__ inline unsigned char f8b(float v) {
#if __has_builtin(__builtin_amdgcn_cvt_pk_fp8_f32)
  int r = __builtin_amdgcn_cvt_pk_fp8_f32(v, v, 0, false);
  return (unsigned char)(r & 0xff);
#else
  __hip_fp8_e4m3 h(v); return h.__x;
#endif
}

// ---------------- degree / dinv (legacy/fallback paths only) ----------------
// Primary path computes degrees inside the bucketed CSR build: 3.2M random
// global atomicAdds showed 99.8 MB WRITE_SIZE for a 400 KB payload (r1
// counters) -- ~250x amplification, 130 us. Bucket-histogram replaces it.

static __global__ void deg_i_kernel(const int* __restrict__ dst, int* __restrict__ deg, int E) {
  int e = blockIdx.x * blockDim.x + threadIdx.x;
  if (e < E) atomicAdd(&deg[dst[e]], 1);
}

static __global__ void dinv_kernel(const int* __restrict__ deg, float* __restrict__ dinv, int N) {
  int i = blockIdx.x * blockDim.x + threadIdx.x;
  if (i < N) dinv[i] = rsqrtf((float)deg[i] + 1.0f);
}

// ---------------- weight preconversion to bf16 ----------------
static __global__ void w1conv_kernel(const float* __restrict__ w1, short* __restrict__ w1bf) {
  int t = blockIdx.x * blockDim.x + threadIdx.x;  // 32768
  if (t >= NFEAT * HID) return;
  int k = t >> 6, n = t & 63;
  w1bf[n * NFEAT + k] = bfs(w1[k * HID + n]);
}
static __global__ void w2conv_kernel(const float* __restrict__ w2, short* __restrict__ w2bf) {
  int t = blockIdx.x * blockDim.x + threadIdx.x;  // 3072
  if (t >= 48 * HID) return;
  int n = t >> 6, k = t & 63;
  w2bf[t] = (n < NCLS) ? bfs(w2[k * NCLS + n]) : (short)0;
}

// ---------------- MFMA MLP ----------------
// Block: 256 threads (4 waves), 64 rows. Writes y0 = dinv*h as fp8 (64 B row stride)
// and out = g0*h (f32).
static __global__ __launch_bounds__(256) void mlp_mfma_kernel(
    const float* __restrict__ x, const short* __restrict__ w1bf, const float* __restrict__ b1,
    const short* __restrict__ w2bf, const float* __restrict__ b2, const float* __restrict__ temp,
    const float* __restrict__ dinv, unsigned char* __restrict__ cur, float* __restrict__ out, int N)
{
  __shared__ __align__(16) short Al[64][72];
  __shared__ __align__(16) short Bl[64][72];
  __shared__ __align__(16) short Hl[64][72];
  __shared__ __align__(16) short W2l[48][72];
  const int tid = threadIdx.x;
  const int w = tid >> 6, lane = tid & 63;
  const int q = lane >> 4, m = lane & 15;
  const long row0 = (long)blockIdx.x * 64;

  if (tid < 192) {
    int n = tid >> 2, ch = tid & 3;
    const int4* sp = (const int4*)(w2bf + n * 64 + ch * 16);
    *(int4*)&W2l[n][ch * 16]     = sp[0];
    *(int4*)&W2l[n][ch * 16 + 8] = sp[1];
  }

  f32x4 zf = {0.f, 0.f, 0.f, 0.f};
  f32x4 acc[4] = {zf, zf, zf, zf};

  const int ar = tid >> 2, ch = tid & 3;
  const long gr = row0 + ar;

  for (int kk = 0; kk < NFEAT; kk += 64) {
    float4 v0, v1, v2, v3;
    if (gr < N) {
      const float4* xp = (const float4*)(x + gr * NFEAT + kk + ch * 16);
      v0 = xp[0]; v1 = xp[1]; v2 = xp[2]; v3 = xp[3];
    } else {
      v0 = v1 = v2 = v3 = make_float4(0.f, 0.f, 0.f, 0.f);
    }
    const int4* bp = (const int4*)(w1bf + ar * NFEAT + kk + ch * 16);
    int4 bv0 = bp[0], bv1 = bp[1];

    __syncthreads();
    int4 a0 = make_int4(pk(v0.x, v0.y), pk(v0.z, v0.w), pk(v1.x, v1.y), pk(v1.z, v1.w));
    int4 a1 = make_int4(pk(v2.x, v2.y), pk(v2.z, v2.w), pk(v3.x, v3.y), pk(v3.z, v3.w));
    *(int4*)&Al[ar][ch * 16]     = a0;
    *(int4*)&Al[ar][ch * 16 + 8] = a1;
    *(int4*)&Bl[ar][ch * 16]     = bv0;
    *(int4*)&Bl[ar][ch * 16 + 8] = bv1;
    __syncthreads();

    #pragma unroll
    for (int s = 0; s < 2; ++s) {
      bf16x8 a = *(const bf16x8*)&Al[w * 16 + m][s * 32 + q * 8];
      #pragma unroll
      for (int c = 0; c < 4; ++c) {
        bf16x8 b = *(const bf16x8*)&Bl[c * 16 + m][s * 32 + q * 8];
        acc[c] = __builtin_amdgcn_mfma_f32_16x16x32_bf16(a, b, acc[c], 0, 0, 0);
      }
    }
  }

  #pragma unroll
  for (int c = 0; c < 4; ++c) {
    int col = c * 16 + m;
    float bb = b1[col];
    #pragma unroll
    for (int r = 0; r < 4; ++r) {
      int rl = w * 16 + q * 4 + r;
      Hl[rl][col] = bfs(fmaxf(acc[c][r] + bb, 0.0f));
    }
  }
  __syncthreads();

  f32x4 acc2[3] = {zf, zf, zf};
  #pragma unroll
  for (int s = 0; s < 2; ++s) {
    bf16x8 a = *(const bf16x8*)&Hl[w * 16 + m][s * 32 + q * 8];
    #pragma unroll
    for (int c = 0; c < 3; ++c) {
      bf16x8 b = *(const bf16x8*)&W2l[c * 16 + m][s * 32 + q * 8];
      acc2[c] = __builtin_amdgcn_mfma_f32_16x16x32_bf16(a, b, acc2[c], 0, 0, 0);
    }
  }

  float g0 = fmaxf(temp[0], 0.0f);
  #pragma unroll
  for (int c = 0; c < 3; ++c) {
    int col = c * 16 + m;
    if (col < NCLS) {
      float bb = b2[col];
      #pragma unroll
      for (int r = 0; r < 4; ++r) {
        long grow = row0 + w * 16 + q * 4 + r;
        if (grow < N) {
          float vv = acc2[c][r] + bb;
          cur[grow * 64 + col] = f8b(dinv[grow] * vv);  // y0 = dinv*h, fp8
          out[grow * NCLS + col] = g0 * vv;
        }
      }
    }
  }
}

// ---------------- legacy scan kernels (fallback paths only) ----------------

static __global__ __launch_bounds__(256) void scan1_kernel(const int* __restrict__ deg,
                                                           int* __restrict__ bsum, int N) {
  __shared__ int s[256];
  int tid = threadIdx.x;
  int i = blockIdx.x * 256 + tid;
  s[tid] = (i < N) ? deg[i] : 0;
  __syncthreads();
  for (int off = 128; off > 0; off >>= 1) {
    if (tid < off) s[tid] += s[tid + off];
    __syncthreads();
  }
  if (tid == 0) bsum[blockIdx.x] = s[0];
}

static __global__ __launch_bounds__(512) void scan2_kernel(int* __restrict__ bsum,
                                                           int* __restrict__ total, int nb) {
  __shared__ int s[512];
  int tid = threadIdx.x;
  int v = (tid < nb) ? bsum[tid] : 0;
  s[tid] = v;
  __syncthreads();
  for (int off = 1; off < 512; off <<= 1) {
    int t = (tid >= off) ? s[tid - off] : 0;
    __syncthreads();
    s[tid] += t;
    __syncthreads();
  }
  if (tid < nb) bsum[tid] = s[tid] - v;
  if (tid == 511) *total = s[511];
}

static __global__ __launch_bounds__(256) void scan3_kernel(const int* __restrict__ deg,
                                                           const int* __restrict__ bsum,
                                                           const int* __restrict__ total,
                                                           int* __restrict__ rowptr,
                                                           int* __restrict__ cursor, int N) {
  __shared__ int s[256];
  int tid = threadIdx.x;
  int i = blockIdx.x * 256 + tid;
  int v = (i < N) ? deg[i] : 0;
  s[tid] = v;
  __syncthreads();
  for (int off = 1; off < 256; off <<= 1) {
    int t = (tid >= off) ? s[tid - off] : 0;
    __syncthreads();
    s[tid] += t;
    __syncthreads();
  }
  if (i < N) {
    int e = bsum[blockIdx.x] + s[tid] - v;
    rowptr[i] = e;
    cursor[i] = e;
  }
  if (i == N) rowptr[N] = *total;
}

// ---------------- CSR build: bucketed counting sort (deg/dinv/rowptr fused) --
//   Buckets = 256-node dst ranges. Pipeline:
//   bcount: per-block LDS bucket histogram -> 1 global atomic/bucket/block
//           (replaces deg_i's 3.2M random atomics, r1: 99.8 MB write amp).
//   bscan:  exclusive scan of bucket totals -> bbase/bcur; rowptr[N]=E.
//   fill_bin: stage edges grouped by bucket in LDS, write packed
//           (src | (dst&255)<<17) runs into csr (src < 2^17).
//   fill_scatter2: one block/bucket; per-node LDS histogram of packed data
//           -> dinv + rowptr (fuses dinv/scan1-3), then LDS reorder in place.

#define FB_EPT 16
#define FB_EPB (256 * FB_EPT)   // 4096 edges/block
#define FB_NBMAX 512            // supports N <= 131072
#define FS_CAP 12288            // bucket capacity (uniform input: ~8200 +- 90)

static __global__ __launch_bounds__(256) void bcount_kernel(
    const int* __restrict__ dst, int* __restrict__ bcnt, int E, int NB)
{
  __shared__ int cnt[FB_NBMAX];
  const int tid = threadIdx.x;
  cnt[tid] = 0; cnt[tid + 256] = 0;
  __syncthreads();
  const int e0 = blockIdx.x * FB_EPB;
  #pragma unroll
  for (int j = 0; j < FB_EPT; ++j) {
    int e = e0 + j * 256 + tid;
    if (e < E) atomicAdd(&cnt[dst[e] >> 8], 1);
  }
  __syncthreads();
  int b0 = tid, b1 = tid + 256;
  if (b0 < NB && cnt[b0]) atomicAdd(&bcnt[b0], cnt[b0]);
  if (b1 < NB && cnt[b1]) atomicAdd(&bcnt[b1], cnt[b1]);
}

static __global__ __launch_bounds__(512) void bscan_kernel(
    const int* __restrict__ bcnt, int* __restrict__ bbase, int* __restrict__ bcur,
    int* __restrict__ rowptr, int NB, int N, int E)
{
  __shared__ int s[512];
  int tid = threadIdx.x;
  int v = (tid < NB) ? bcnt[tid] : 0;
  s[tid] = v;
  __syncthreads();
  for (int off = 1; off < 512; off <<= 1) {
    int t = (tid >= off) ? s[tid - off] : 0;
    __syncthreads();
    s[tid] += t;
    __syncthreads();
  }
  if (tid < NB) { int ex = s[tid] - v; bbase[tid] = ex; bcur[tid] = ex; }
  if (tid == 0) rowptr[N] = E;
}

static __global__ __launch_bounds__(256) void fill_bin_kernel(
    const int* __restrict__ src, const int* __restrict__ dst,
    int* __restrict__ bcur, int* __restrict__ csr, int E, int NB)
{
  __shared__ int cnt[FB_NBMAX];
  __shared__ int pfx[FB_NBMAX];
  __shared__ int gbase[FB_NBMAX];
  __shared__ int stg[FB_EPB];
  __shared__ unsigned short bmap[FB_EPB];
  const int tid = threadIdx.x;
  const int e0 = blockIdx.x * FB_EPB;

  cnt[tid] = 0; cnt[tid + 256] = 0;
  __syncthreads();

  int pk_[FB_EPT], b_[FB_EPT], r_[FB_EPT];
  #pragma unroll
  for (int j = 0; j < FB_EPT; ++j) {
    int e = e0 + j * 256 + tid;  // coalesced
    if (e < E) {
      int s = src[e], d = dst[e];
      pk_[j] = s | ((d & 255) << 17);
      b_[j] = d >> 8;
      r_[j] = atomicAdd(&cnt[b_[j]], 1);
    } else b_[j] = -1;
  }
  __syncthreads();

  // inclusive Hillis-Steele scan of cnt into pfx (512 entries, 2/thread)
  pfx[tid] = cnt[tid]; pfx[tid + 256] = cnt[tid + 256];
  __syncthreads();
  for (int off = 1; off < FB_NBMAX; off <<= 1) {
    int a = (tid >= off) ? pfx[tid - off] : 0;
    int b = (tid + 256 >= off) ? pfx[tid + 256 - off] : 0;
    __syncthreads();
    pfx[tid] += a; pfx[tid + 256] += b;
    __syncthreads();
  }

  // reserve global space: one atomic per non-empty bucket
  {
    int b0 = tid, b1 = tid + 256;
    if (b0 < NB && cnt[b0]) gbase[b0] = atomicAdd(&bcur[b0], cnt[b0]);
    if (b1 < NB && cnt[b1]) gbase[b1] = atomicAdd(&bcur[b1], cnt[b1]);
  }
  __syncthreads();

  // place into LDS staging grouped by bucket
  #pragma unroll
  for (int j = 0; j < FB_EPT; ++j) {
    if (b_[j] >= 0) {
      int slot = pfx[b_[j]] - cnt[b_[j]] + r_[j];
      stg[slot] = pk_[j];
      bmap[slot] = (unsigned short)b_[j];
    }
  }
  __syncthreads();

  // copy out: consecutive slots -> consecutive global addresses within a run
  const int total = pfx[FB_NBMAX - 1];
  for (int slot = tid; slot < total; slot += 256) {
    int b = bmap[slot];
    int local = slot - (pfx[b] - cnt[b]);
    csr[gbase[b] + local] = stg[slot];
  }
}

static __global__ __launch_bounds__(256) void fill_scatter2_kernel(
    const int* __restrict__ bbase_a, const int* __restrict__ bcnt,
    int* __restrict__ csr, const int* __restrict__ src, const int* __restrict__ dst,
    float* __restrict__ dinv, int* __restrict__ rowptr, int N, int E)
{
  __shared__ int degl[256];
  __shared__ int pfx[256];
  __shared__ int curl[256];
  __shared__ int buf[FS_CAP];
  const int tid = threadIdx.x;
  const int b = blockIdx.x;
  const int base = bbase_a[b], cnt = bcnt[b];
  const int node = (b << 8) + tid;

  degl[tid] = 0;
  __syncthreads();
  if (cnt <= FS_CAP) {
    for (int i = tid; i < cnt; i += 256) {
      int p = csr[base + i];
      atomicAdd(&degl[(p >> 17) & 255], 1);
    }
  } else {
    // overflow safety net (P~0): recount from raw edge list
    for (int e = tid; e < E; e += 256) {
      int d = dst[e];
      if ((d >> 8) == b) atomicAdd(&degl[d & 255], 1);
    }
  }
  __syncthreads();
  const int dv = degl[tid];
  if (node < N) dinv[node] = rsqrtf((float)dv + 1.0f);

  // exclusive scan of degl
  pfx[tid] = dv;
  __syncthreads();
  for (int off = 1; off < 256; off <<= 1) {
    int t = (tid >= off) ? pfx[tid - off] : 0;
    __syncthreads();
    pfx[tid] += t;
    __syncthreads();
  }
  const int ex = pfx[tid] - dv;
  if (node < N) rowptr[node] = base + ex;
  curl[tid] = ex;
  __syncthreads();

  if (cnt <= FS_CAP) {
    for (int i = tid; i < cnt; i += 256) {
      int p = csr[base + i];
      int ld = (p >> 17) & 255;
      int pos = atomicAdd(&curl[ld], 1);
      buf[pos] = p & 0x1FFFF;
    }
    __syncthreads();
    for (int i = tid; i < cnt; i += 256) csr[base + i] = buf[i];
  } else {
    curl[tid] = base + ex;
    __syncthreads();
    for (int e = tid; e < E; e += 256) {
      int d = dst[e];
      if ((d >> 8) == b) {
        int pos = atomicAdd(&curl[d & 255], 1);
        csr[pos] = src[e];
      }
    }
  }
}

// ---------------- legacy atomic-scatter fill (fallback when NB > FB_NBMAX) ---

static __global__ void fill_kernel(const int* __restrict__ src, const int* __restrict__ dst,
                                   int* __restrict__ cursor, int* __restrict__ csr, int E) {
  int e = blockIdx.x * blockDim.x + threadIdx.x;
  if (e >= E) return;
  int s = src[e], d = dst[e];
  int pos = atomicAdd(&cursor[d], 1);
  csr[pos] = s;
}

// ---------------- fused propagation step (CSR gather, y-form, fp8, unroll-8) ----------
// cur rows: 40 fp8 bytes padded to 64 B stride -> exactly ONE cache line per edge.
// y' = dinv^2 * (y[row] + sum y[src]);  out += gamma*dinv*(y[row] + sum y[src])

static __global__ __launch_bounds__(256) void gather_kernel(
    const int* __restrict__ rowptr, const int* __restrict__ csr,
    const float* __restrict__ dinv, const float* __restrict__ temp, int k,
    const unsigned char* __restrict__ cur, unsigned char* __restrict__ nxt,
    float4* __restrict__ out, int n5)
{
  int t = blockIdx.x * blockDim.x + threadIdx.x;
  if (t >= n5) return;
  int row = t / 5, c4 = t - row * 5;
  int c8 = c4 * 8;
  int beg = rowptr[row], end = rowptr[row + 1];
  float dv = dinv[row];

  float a[8];
  up8f8(*(const int2*)(cur + (row << 6) + c8), a);   // self term y[row]

  int e = beg;
  // unroll-8: phase-separated (8 idx loads -> 8 gathers -> accumulate)
  for (; e + 7 < end; e += 8) {
    int idx[8];
    #pragma unroll
    for (int j = 0; j < 8; ++j) idx[j] = __builtin_nontemporal_load(csr + e + j);
    int2 g[8];
    #pragma unroll
    for (int j = 0; j < 8; ++j) g[j] = *(const int2*)(cur + ((long)idx[j] << 6) + c8);
    #pragma unroll
    for (int j = 0; j < 8; ++j) {
      float u[8];
      up8f8(g[j], u);
      #pragma unroll
      for (int i = 0; i < 8; ++i) a[i] += u[i];
    }
  }
  for (; e + 1 < end; e += 2) {
    int i0 = __builtin_nontemporal_load(csr + e);
    int i1 = __builtin_nontemporal_load(csr + e + 1);
    int2 g0 = *(const int2*)(cur + ((long)i0 << 6) + c8);
    int2 g1 = *(const int2*)(cur + ((long)i1 << 6) + c8);
    float u0[8], u1[8];
    up8f8(g0, u0); up8f8(g1, u1);
    #pragma unroll
    for (int i = 0; i < 8; ++i) a[i] += u0[i] + u1[i];
  }
  if (e < end) {
    int i0 = __builtin_nontemporal_load(csr + e);
    float u0[8];
    up8f8(*(const int2*)(cur + ((long)i0 << 6) + c8), u0);
    #pragma unroll
    for (int i = 0; i < 8; ++i) a[i] += u0[i];
  }

  float d2 = dv * dv;
  float y[8];
  #pragma unroll
  for (int i = 0; i < 8; ++i) y[i] = d2 * a[i];
  *(int2*)(nxt + (row << 6) + c8) = pk8f8(y);

  float gd = fmaxf(temp[k], 0.0f) * dv;   // gamma * dinv
  int oi = row * 10 + c4 * 2;
  float4 o0 = out[oi], o1 = out[oi + 1];
  out[oi]     = make_float4(fmaf(gd, a[0], o0.x), fmaf(gd, a[1], o0.y), fmaf(gd, a[2], o0.z), fmaf(gd, a[3], o0.w));
  out[oi + 1] = make_float4(fmaf(gd, a[4], o1.x), fmaf(gd, a[5], o1.y), fmaf(gd, a[6], o1.z), fmaf(gd, a[7], o1.w));
}

// ---------------- fallback scatter path (only if ws too small) ----------------

static __global__ void selfloop_kernel(const float* __restrict__ dinv, const float4* __restrict__ cur,
                                       float4* __restrict__ nxt, int n10) {
  int t = blockIdx.x * blockDim.x + threadIdx.x;
  if (t >= n10) return;
  int i = t / 10;
  float dv = dinv[i], s = dv * dv;
  float4 v = cur[t];
  nxt[t] = make_float4(s * v.x, s * v.y, s * v.z, s * v.w);
}

static __global__ void scatter_kernel(const int* __restrict__ src, const int* __restrict__ dst,
                                      const float* __restrict__ dinv,
                                      const float4* __restrict__ cur, float* __restrict__ nxt, int items) {
  int t = blockIdx.x * blockDim.x + threadIdx.x;
  if (t >= items) return;
  int e = t / 10, c4 = t - e * 10;
  int s = src[e], d = dst[e];
  float nm = dinv[s] * dinv[d];
  float4 v = cur[s * 10 + c4];
  float* np = nxt + (size_t)d * NCLS + c4 * 4;
  unsafeAtomicAdd(np + 0, nm * v.x);
  unsafeAtomicAdd(np + 1, nm * v.y);
  unsafeAtomicAdd(np + 2, nm * v.z);
  unsafeAtomicAdd(np + 3, nm * v.w);
}

static __global__ void axpy_kernel(const float* __restrict__ temp, int k,
                                   const float4* __restrict__ nxt, float4* __restrict__ out, int n10) {
  int t = blockIdx.x * blockDim.x + threadIdx.x;
  if (t >= n10) return;
  float g = fmaxf(temp[k], 0.0f);
  float4 v = nxt[t], o = out[t];
  out[t] = make_float4(o.x + g * v.x, o.y + g * v.y, o.z + g * v.z, o.w + g * v.w);
}

static __global__ __launch_bounds__(256) void mlp_kernel(
    const float* __restrict__ x, const float* __restrict__ w1, const float* __restrict__ b1,
    const float* __restrict__ w2, const float* __restrict__ b2, const float* __restrict__ temp,
    float* __restrict__ cur, float* __restrict__ out, int N)
{
  __shared__ __align__(16) float xs[4][NFEAT];
  __shared__ float hs[4][HID];
  const int w = threadIdx.x >> 6, lane = threadIdx.x & 63;
  const int i = blockIdx.x * 4 + w;
  if (i < N) {
    const float4* xrow = (const float4*)(x + (size_t)i * NFEAT);
    float4* xsr = (float4*)xs[w];
    xsr[lane]      = xrow[lane];
    xsr[lane + 64] = xrow[lane + 64];
  }
  __syncthreads();
  if (i < N) {
    float acc = b1[lane];
    #pragma unroll 8
    for (int k = 0; k < NFEAT; ++k)
      acc = fmaf(xs[w][k], w1[k * HID + lane], acc);
    hs[w][lane] = fmaxf(acc, 0.0f);
  }
  __syncthreads();
  if (i < N && lane < NCLS) {
    float a2 = b2[lane];
    #pragma unroll
    for (int j = 0; j < HID; ++j)
      a2 = fmaf(hs[w][j], w2[j * NCLS + lane], a2);
    float g0 = fmaxf(temp[0], 0.0f);
    cur[(size_t)i * NCLS + lane] = a2;
    out[(size_t)i * NCLS + lane] = g0 * a2;
  }
}

// ---------------- log_softmax ----------------
static __global__ void logsoftmax_kernel(float* __restrict__ out, int N) {
  int i = blockIdx.x * blockDim.x + threadIdx.x;
  if (i >= N) return;
  float4* row = (float4*)(out + (size_t)i * NCLS);
  float4 v[10];
  float m = -3.4e38f;
  #pragma unroll
  for (int r = 0; r < 10; ++r) {
    v[r] = row[r];
    m = fmaxf(m, fmaxf(fmaxf(v[r].x, v[r].y), fmaxf(v[r].z, v[r].w)));
  }
  float sum = 0.0f;
  #pragma unroll
  for (int r = 0; r < 10; ++r)
    sum += __expf(v[r].x - m) + __expf(v[r].y - m) + __expf(v[r].z - m) + __expf(v[r].w - m);
  float l = m + __logf(sum);
  #pragma unroll
  for (int r = 0; r < 10; ++r)
    row[r] = make_float4(v[r].x - l, v[r].y - l, v[r].z - l, v[r].w - l);
}

// ---------------- launch ----------------

extern "C" void kernel_launch(void* const* d_in, const int* in_sizes, int n_in,
                              void* d_out, int out_size, void* d_ws, size_t ws_size,
                              hipStream_t stream) {
  const float* x    = (const float*)d_in[0];
  const int*   ei   = (const int*)d_in[1];
  const float* w1   = (const float*)d_in[2];
  const float* b1   = (const float*)d_in[3];
  const float* w2   = (const float*)d_in[4];
  const float* b2   = (const float*)d_in[5];
  const float* temp = (const float*)d_in[6];

  const int N = in_sizes[0] / NFEAT;   // 100000
  const int E = in_sizes[1] / 2;       // 3200000
  const int* src = ei;
  const int* dst = ei + E;
  float* out = (float*)d_out;

  char* ws = (char*)d_ws;
  size_t off = 0;
  auto alloc = [&](size_t bytes) { size_t o = off; off += (bytes + 255) & ~(size_t)255; return o; };
  float* dinv   = (float*)(ws + alloc((size_t)N * 4));
  int*   deg    = (int*)  (ws + alloc((size_t)N * 4));
  unsigned char* curA = (unsigned char*)(ws + alloc((size_t)N * 64));  // fp8, 64 B rows
  unsigned char* curB = (unsigned char*)(ws + alloc((size_t)N * 64));
  int*   rowptr = (int*)  (ws + alloc((size_t)(N + 1) * 4));
  int*   cursor = (int*)  (ws + alloc((size_t)N * 4));
  int*   bsum   = (int*)  (ws + alloc(1024 * 4));
  int*   total  = (int*)  (ws + alloc(256));
  int*   bcnt   = (int*)  (ws + alloc(FB_NBMAX * 4));
  int*   bbase  = (int*)  (ws + alloc(FB_NBMAX * 4));
  int*   bcur   = (int*)  (ws + alloc(FB_NBMAX * 4));
  short* w1bf   = (short*)(ws + alloc((size_t)NFEAT * HID * 2));
  short* w2bf   = (short*)(ws + alloc((size_t)48 * HID * 2));
  int*   csr    = (int*)  (ws + alloc((size_t)E * 4));
  // fallback needs f32 cur buffers
  float* fA     = (float*)curA;
  const bool csr_ok = (off <= ws_size);

  const int NB = (N + 255) >> 8;  // 256-node buckets

  if (csr_ok && NB <= FB_NBMAX && N <= (1 << 17)) {
    // ---- primary path: deg/dinv/rowptr fused into bucketed CSR build ----
    w1conv_kernel<<<(NFEAT * HID + 255) / 256, 256, 0, stream>>>(w1, w1bf);
    w2conv_kernel<<<(48 * HID + 255) / 256, 256, 0, stream>>>(w2, w2bf);

    hipMemsetAsync(bcnt, 0, (size_t)NB * sizeof(int), stream);
    bcount_kernel<<<(E + FB_EPB - 1) / FB_EPB, 256, 0, stream>>>(dst, bcnt, E, NB);
    bscan_kernel<<<1, 512, 0, stream>>>(bcnt, bbase, bcur, rowptr, NB, N, E);
    fill_bin_kernel<<<(E + FB_EPB - 1) / FB_EPB, 256, 0, stream>>>(src, dst, bcur, csr, E, NB);
    fill_scatter2_kernel<<<NB, 256, 0, stream>>>(bbase, bcnt, csr, src, dst, dinv, rowptr, N, E);

    mlp_mfma_kernel<<<(N + 63) / 64, 256, 0, stream>>>(x, w1bf, b1, w2bf, b2, temp, dinv,
                                                       curA, out, N);

    const int n5 = N * 5;
    unsigned char* cur = curA;
    unsigned char* nxt = curB;
    for (int k = 0; k < 10; ++k) {
      gather_kernel<<<(n5 + 255) / 256, 256, 0, stream>>>(
          rowptr, csr, dinv, temp, k + 1, cur, nxt, (float4*)out, n5);
      unsigned char* t2 = cur; cur = nxt; nxt = t2;
    }
    logsoftmax_kernel<<<(N + 255) / 256, 256, 0, stream>>>(out, N);
    return;
  }

  hipMemsetAsync(deg, 0, (size_t)N * sizeof(int), stream);
  deg_i_kernel<<<(E + 255) / 256, 256, 0, stream>>>(dst, deg, E);
  dinv_kernel<<<(N + 255) / 256, 256, 0, stream>>>(deg, dinv, N);

  if (csr_ok) {
    // ---- legacy CSR path (large N): atomic scatter fill ----
    w1conv_kernel<<<(NFEAT * HID + 255) / 256, 256, 0, stream>>>(w1, w1bf);
    w2conv_kernel<<<(48 * HID + 255) / 256, 256, 0, stream>>>(w2, w2bf);
    mlp_mfma_kernel<<<(N + 63) / 64, 256, 0, stream>>>(x, w1bf, b1, w2bf, b2, temp, dinv,
                                                       curA, out, N);

    const int nb = (N + 255) / 256;
    scan1_kernel<<<nb, 256, 0, stream>>>(deg, bsum, N);
    scan2_kernel<<<1, 512, 0, stream>>>(bsum, total, nb);
    scan3_kernel<<<(N + 256) / 256, 256, 0, stream>>>(deg, bsum, total, rowptr, cursor, N);
    fill_kernel<<<(E + 255) / 256, 256, 0, stream>>>(src, dst, cursor, csr, E);

    const int n5 = N * 5;
    unsigned char* cur = curA;
    unsigned char* nxt = curB;
    for (int k = 0; k < 10; ++k) {
      gather_kernel<<<(n5 + 255) / 256, 256, 0, stream>>>(
          rowptr, csr, dinv, temp, k + 1, cur, nxt, (float4*)out, n5);
      unsigned char* t2 = cur; cur = nxt; nxt = t2;
    }
  } else {
    // f32 fallback (uses curA region as float storage; requires less ws than main path)
    float* fB = (float*)curB;
    mlp_kernel<<<(N + 3) / 4, 256, 0, stream>>>(x, w1, b1, w2, b2, temp, fA, out, N);
    const int n10 = N * 10;
    const int items = E * 10;
    float* cur = fA;
    float* nxt = fB;
    for (int k = 0; k < 10; ++k) {
      selfloop_kernel<<<(n10 + 255) / 256, 256, 0, stream>>>(dinv, (const float4*)cur, (float4*)nxt, n10);
      scatter_kernel<<<(items + 255) / 256, 256, 0, stream>>>(src, dst, dinv, (const float4*)cur, nxt, items);
      axpy_kernel<<<(n10 + 255) / 256, 256, 0, stream>>>(temp, k + 1, (const float4*)nxt, (float4*)out, n10);
      float* t2 = cur; cur = nxt; nxt = t2;
    }
  }

  logsoftmax_kernel<<<(N + 255) / 256, 256, 0, stream>>>(out, N);
}

// Round 4
// 836.986 us; speedup vs baseline: 1.4944x; 1.0971x over previous
//
#include <hip/hip_runtime.h>
#include <hip/hip_bf16.h>
#include <hip/hip_fp16.h>
#include <hip/hip_fp8.h>

#define NFEAT 512
#define HID   64
#define NCLS  40

typedef short bf16x8 __attribute__((ext_vector_type(8)));
typedef float f32x4  __attribute__((ext_vector_type(4)));
typedef float v2f    __attribute__((ext_vector_type(2)));

__device__ inline short bfs(float f) {
  __hip_bfloat16 h = __float2bfloat16(f);
  return __builtin_bit_cast(short, h);
}
__device__ inline int pk(float a, float b) {  // two bf16 packed, a = low half
  return (int)(unsigned short)bfs(a) | ((int)(unsigned short)bfs(b) << 16);
}

// ---- fp8 e4m3 (OCP) pack/unpack ----
// NOTE: __builtin_amdgcn_cvt_pk_f32_fp8's word-select arg must be a LITERAL
// constant at the call site (frontend-checked before inlining) -> two fns.
__device__ inline v2f cvt2lo(int v) {
#if __has_builtin(__builtin_amdgcn_cvt_pk_f32_fp8)
  return __builtin_amdgcn_cvt_pk_f32_fp8(v, false);
#else
  v2f r; const unsigned char* b = (const unsigned char*)&v;
  __hip_fp8_e4m3 h0; h0.__x = b[0]; r[0] = (float)h0;
  __hip_fp8_e4m3 h1; h1.__x = b[1]; r[1] = (float)h1;
  return r;
#endif
}
__device__ inline v2f cvt2hi(int v) {
#if __has_builtin(__builtin_amdgcn_cvt_pk_f32_fp8)
  return __builtin_amdgcn_cvt_pk_f32_fp8(v, true);
#else
  v2f r; const unsigned char* b = (const unsigned char*)&v;
  __hip_fp8_e4m3 h0; h0.__x = b[2]; r[0] = (float)h0;
  __hip_fp8_e4m3 h1; h1.__x = b[3]; r[1] = (float)h1;
  return r;
#endif
}
__device__ inline int2 pk8f8(const float f[8]) {
#if __has_builtin(__builtin_amdgcn_cvt_pk_fp8_f32)
  int lo = 0, hi = 0;
  lo = __builtin_amdgcn_cvt_pk_fp8_f32(f[0], f[1], lo, false);
  lo = __builtin_amdgcn_cvt_pk_fp8_f32(f[2], f[3], lo, true);
  hi = __builtin_amdgcn_cvt_pk_fp8_f32(f[4], f[5], hi, false);
  hi = __builtin_amdgcn_cvt_pk_fp8_f32(f[6], f[7], hi, true);
  return make_int2(lo, hi);
#else
  int2 r; unsigned char* b = (unsigned char*)&r;
  #pragma unroll
  for (int i = 0; i < 8; ++i) { __hip_fp8_e4m3 h((float)f[i]); b[i] = h.__x; }
  return r;
#endif
}
__device__ inline unsigned char f8b(float v) {
#if __has_builtin(__builtin_amdgcn_cvt_pk_fp8_f32)
  int r = __builtin_amdgcn_cvt_pk_fp8_f32(v, v, 0, false);
  return (unsigned char)(r & 0xff);
#else
  __hip_fp8_e4m3 h(v); return h.__x;
#endif
}

// ---------------- degree / dinv (legacy/fallback paths only) ----------------

static __global__ void deg_i_kernel(const int* __restrict__ dst, int* __restrict__ deg, int E) {
  int e = blockIdx.x * blockDim.x + threadIdx.x;
  if (e < E) atomicAdd(&deg[dst[e]], 1);
}

static __global__ void dinv_kernel(const int* __restrict__ deg, float* __restrict__ dinv, int N) {
  int i = blockIdx.x * blockDim.x + threadIdx.x;
  if (i < N) dinv[i] = rsqrtf((float)deg[i] + 1.0f);
}

// ---------------- weight preconversion to bf16 (+ bcnt zeroing fused) -------
static __global__ void w1conv_kernel(const float* __restrict__ w1, short* __restrict__ w1bf,
                                     int* __restrict__ bcnt, int nbz) {
  int t = blockIdx.x * blockDim.x + threadIdx.x;  // 32768
  if (t < nbz) bcnt[t] = 0;
  if (t >= NFEAT * HID) return;
  int k = t >> 6, n = t & 63;
  w1bf[n * NFEAT + k] = bfs(w1[k * HID + n]);
}
static __global__ void w2conv_kernel(const float* __restrict__ w2, short* __restrict__ w2bf) {
  int t = blockIdx.x * blockDim.x + threadIdx.x;  // 3072
  if (t >= 48 * HID) return;
  int n = t >> 6, k = t & 63;
  w2bf[t] = (n < NCLS) ? bfs(w2[k * NCLS + n]) : (short)0;
}

// ---------------- MFMA MLP ----------------
static __global__ __launch_bounds__(256) void mlp_mfma_kernel(
    const float* __restrict__ x, const short* __restrict__ w1bf, const float* __restrict__ b1,
    const short* __restrict__ w2bf, const float* __restrict__ b2, const float* __restrict__ temp,
    const float* __restrict__ dinv, unsigned char* __restrict__ cur, float* __restrict__ out, int N)
{
  __shared__ __align__(16) short Al[64][72];
  __shared__ __align__(16) short Bl[64][72];
  __shared__ __align__(16) short Hl[64][72];
  __shared__ __align__(16) short W2l[48][72];
  const int tid = threadIdx.x;
  const int w = tid >> 6, lane = tid & 63;
  const int q = lane >> 4, m = lane & 15;
  const long row0 = (long)blockIdx.x * 64;

  if (tid < 192) {
    int n = tid >> 2, ch = tid & 3;
    const int4* sp = (const int4*)(w2bf + n * 64 + ch * 16);
    *(int4*)&W2l[n][ch * 16]     = sp[0];
    *(int4*)&W2l[n][ch * 16 + 8] = sp[1];
  }

  f32x4 zf = {0.f, 0.f, 0.f, 0.f};
  f32x4 acc[4] = {zf, zf, zf, zf};

  const int ar = tid >> 2, ch = tid & 3;
  const long gr = row0 + ar;

  for (int kk = 0; kk < NFEAT; kk += 64) {
    float4 v0, v1, v2, v3;
    if (gr < N) {
      const float4* xp = (const float4*)(x + gr * NFEAT + kk + ch * 16);
      v0 = xp[0]; v1 = xp[1]; v2 = xp[2]; v3 = xp[3];
    } else {
      v0 = v1 = v2 = v3 = make_float4(0.f, 0.f, 0.f, 0.f);
    }
    const int4* bp = (const int4*)(w1bf + ar * NFEAT + kk + ch * 16);
    int4 bv0 = bp[0], bv1 = bp[1];

    __syncthreads();
    int4 a0 = make_int4(pk(v0.x, v0.y), pk(v0.z, v0.w), pk(v1.x, v1.y), pk(v1.z, v1.w));
    int4 a1 = make_int4(pk(v2.x, v2.y), pk(v2.z, v2.w), pk(v3.x, v3.y), pk(v3.z, v3.w));
    *(int4*)&Al[ar][ch * 16]     = a0;
    *(int4*)&Al[ar][ch * 16 + 8] = a1;
    *(int4*)&Bl[ar][ch * 16]     = bv0;
    *(int4*)&Bl[ar][ch * 16 + 8] = bv1;
    __syncthreads();

    #pragma unroll
    for (int s = 0; s < 2; ++s) {
      bf16x8 a = *(const bf16x8*)&Al[w * 16 + m][s * 32 + q * 8];
      #pragma unroll
      for (int c = 0; c < 4; ++c) {
        bf16x8 b = *(const bf16x8*)&Bl[c * 16 + m][s * 32 + q * 8];
        acc[c] = __builtin_amdgcn_mfma_f32_16x16x32_bf16(a, b, acc[c], 0, 0, 0);
      }
    }
  }

  #pragma unroll
  for (int c = 0; c < 4; ++c) {
    int col = c * 16 + m;
    float bb = b1[col];
    #pragma unroll
    for (int r = 0; r < 4; ++r) {
      int rl = w * 16 + q * 4 + r;
      Hl[rl][col] = bfs(fmaxf(acc[c][r] + bb, 0.0f));
    }
  }
  __syncthreads();

  f32x4 acc2[3] = {zf, zf, zf};
  #pragma unroll
  for (int s = 0; s < 2; ++s) {
    bf16x8 a = *(const bf16x8*)&Hl[w * 16 + m][s * 32 + q * 8];
    #pragma unroll
    for (int c = 0; c < 3; ++c) {
      bf16x8 b = *(const bf16x8*)&W2l[c * 16 + m][s * 32 + q * 8];
      acc2[c] = __builtin_amdgcn_mfma_f32_16x16x32_bf16(a, b, acc2[c], 0, 0, 0);
    }
  }

  float g0 = fmaxf(temp[0], 0.0f);
  #pragma unroll
  for (int c = 0; c < 3; ++c) {
    int col = c * 16 + m;
    if (col < NCLS) {
      float bb = b2[col];
      #pragma unroll
      for (int r = 0; r < 4; ++r) {
        long grow = row0 + w * 16 + q * 4 + r;
        if (grow < N) {
          float vv = acc2[c][r] + bb;
          cur[grow * 64 + col] = f8b(dinv[grow] * vv);  // y0 = dinv*h, fp8
          out[grow * NCLS + col] = g0 * vv;
        }
      }
    }
  }
}

// ---------------- legacy scan kernels (fallback paths only) ----------------

static __global__ __launch_bounds__(256) void scan1_kernel(const int* __restrict__ deg,
                                                           int* __restrict__ bsum, int N) {
  __shared__ int s[256];
  int tid = threadIdx.x;
  int i = blockIdx.x * 256 + tid;
  s[tid] = (i < N) ? deg[i] : 0;
  __syncthreads();
  for (int off = 128; off > 0; off >>= 1) {
    if (tid < off) s[tid] += s[tid + off];
    __syncthreads();
  }
  if (tid == 0) bsum[blockIdx.x] = s[0];
}

static __global__ __launch_bounds__(512) void scan2_kernel(int* __restrict__ bsum,
                                                           int* __restrict__ total, int nb) {
  __shared__ int s[512];
  int tid = threadIdx.x;
  int v = (tid < nb) ? bsum[tid] : 0;
  s[tid] = v;
  __syncthreads();
  for (int off = 1; off < 512; off <<= 1) {
    int t = (tid >= off) ? s[tid - off] : 0;
    __syncthreads();
    s[tid] += t;
    __syncthreads();
  }
  if (tid < nb) bsum[tid] = s[tid] - v;
  if (tid == 511) *total = s[511];
}

static __global__ __launch_bounds__(256) void scan3_kernel(const int* __restrict__ deg,
                                                           const int* __restrict__ bsum,
                                                           const int* __restrict__ total,
                                                           int* __restrict__ rowptr,
                                                           int* __restrict__ cursor, int N) {
  __shared__ int s[256];
  int tid = threadIdx.x;
  int i = blockIdx.x * 256 + tid;
  int v = (i < N) ? deg[i] : 0;
  s[tid] = v;
  __syncthreads();
  for (int off = 1; off < 256; off <<= 1) {
    int t = (tid >= off) ? s[tid - off] : 0;
    __syncthreads();
    s[tid] += t;
    __syncthreads();
  }
  if (i < N) {
    int e = bsum[blockIdx.x] + s[tid] - v;
    rowptr[i] = e;
    cursor[i] = e;
  }
  if (i == N) rowptr[N] = *total;
}

// ---------------- CSR build: bucketed counting sort (deg/dinv/rowptr fused) --

#define FB_EPT 16
#define FB_EPB (256 * FB_EPT)   // 4096 edges/block
#define FB_NBMAX 512            // supports N <= 131072
#define FS_CAP 12288            // bucket capacity (uniform input: ~8200 +- 90)

static __global__ __launch_bounds__(256) void bcount_kernel(
    const int* __restrict__ dst, int* __restrict__ bcnt, int E, int NB)
{
  __shared__ int cnt[FB_NBMAX];
  const int tid = threadIdx.x;
  cnt[tid] = 0; cnt[tid + 256] = 0;
  __syncthreads();
  const int e0 = blockIdx.x * FB_EPB;
  #pragma unroll
  for (int j = 0; j < FB_EPT; ++j) {
    int e = e0 + j * 256 + tid;
    if (e < E) atomicAdd(&cnt[dst[e] >> 8], 1);
  }
  __syncthreads();
  int b0 = tid, b1 = tid + 256;
  if (b0 < NB && cnt[b0]) atomicAdd(&bcnt[b0], cnt[b0]);
  if (b1 < NB && cnt[b1]) atomicAdd(&bcnt[b1], cnt[b1]);
}

static __global__ __launch_bounds__(512) void bscan_kernel(
    const int* __restrict__ bcnt, int* __restrict__ bbase, int* __restrict__ bcur,
    int* __restrict__ rowptr, int NB, int N, int E)
{
  __shared__ int s[512];
  int tid = threadIdx.x;
  int v = (tid < NB) ? bcnt[tid] : 0;
  s[tid] = v;
  __syncthreads();
  for (int off = 1; off < 512; off <<= 1) {
    int t = (tid >= off) ? s[tid - off] : 0;
    __syncthreads();
    s[tid] += t;
    __syncthreads();
  }
  if (tid < NB) { int ex = s[tid] - v; bbase[tid] = ex; bcur[tid] = ex; }
  if (tid == 0) rowptr[N] = E;
}

static __global__ __launch_bounds__(256) void fill_bin_kernel(
    const int* __restrict__ src, const int* __restrict__ dst,
    int* __restrict__ bcur, int* __restrict__ csr, int E, int NB)
{
  __shared__ int cnt[FB_NBMAX];
  __shared__ int pfx[FB_NBMAX];
  __shared__ int gbase[FB_NBMAX];
  __shared__ int stg[FB_EPB];
  __shared__ unsigned short bmap[FB_EPB];
  const int tid = threadIdx.x;
  const int e0 = blockIdx.x * FB_EPB;

  cnt[tid] = 0; cnt[tid + 256] = 0;
  __syncthreads();

  int pk_[FB_EPT], b_[FB_EPT], r_[FB_EPT];
  #pragma unroll
  for (int j = 0; j < FB_EPT; ++j) {
    int e = e0 + j * 256 + tid;  // coalesced
    if (e < E) {
      int s = src[e], d = dst[e];
      pk_[j] = s | ((d & 255) << 17);
      b_[j] = d >> 8;
      r_[j] = atomicAdd(&cnt[b_[j]], 1);
    } else b_[j] = -1;
  }
  __syncthreads();

  // inclusive Hillis-Steele scan of cnt into pfx (512 entries, 2/thread)
  pfx[tid] = cnt[tid]; pfx[tid + 256] = cnt[tid + 256];
  __syncthreads();
  for (int off = 1; off < FB_NBMAX; off <<= 1) {
    int a = (tid >= off) ? pfx[tid - off] : 0;
    int b = (tid + 256 >= off) ? pfx[tid + 256 - off] : 0;
    __syncthreads();
    pfx[tid] += a; pfx[tid + 256] += b;
    __syncthreads();
  }

  // reserve global space: one atomic per non-empty bucket
  {
    int b0 = tid, b1 = tid + 256;
    if (b0 < NB && cnt[b0]) gbase[b0] = atomicAdd(&bcur[b0], cnt[b0]);
    if (b1 < NB && cnt[b1]) gbase[b1] = atomicAdd(&bcur[b1], cnt[b1]);
  }
  __syncthreads();

  // place into LDS staging grouped by bucket
  #pragma unroll
  for (int j = 0; j < FB_EPT; ++j) {
    if (b_[j] >= 0) {
      int slot = pfx[b_[j]] - cnt[b_[j]] + r_[j];
      stg[slot] = pk_[j];
      bmap[slot] = (unsigned short)b_[j];
    }
  }
  __syncthreads();

  // copy out: consecutive slots -> consecutive global addresses within a run
  const int total = pfx[FB_NBMAX - 1];
  for (int slot = tid; slot < total; slot += 256) {
    int b = bmap[slot];
    int local = slot - (pfx[b] - cnt[b]);
    csr[gbase[b] + local] = stg[slot];
  }
}

static __global__ __launch_bounds__(256) void fill_scatter2_kernel(
    const int* __restrict__ bbase_a, const int* __restrict__ bcnt,
    int* __restrict__ csr, const int* __restrict__ src, const int* __restrict__ dst,
    float* __restrict__ dinv, int* __restrict__ rowptr, int N, int E)
{
  __shared__ int degl[256];
  __shared__ int pfx[256];
  __shared__ int curl[256];
  __shared__ int buf[FS_CAP];
  const int tid = threadIdx.x;
  const int b = blockIdx.x;
  const int base = bbase_a[b], cnt = bcnt[b];
  const int node = (b << 8) + tid;

  degl[tid] = 0;
  __syncthreads();
  if (cnt <= FS_CAP) {
    for (int i = tid; i < cnt; i += 256) {
      int p = csr[base + i];
      atomicAdd(&degl[(p >> 17) & 255], 1);
    }
  } else {
    // overflow safety net (P~0): recount from raw edge list
    for (int e = tid; e < E; e += 256) {
      int d = dst[e];
      if ((d >> 8) == b) atomicAdd(&degl[d & 255], 1);
    }
  }
  __syncthreads();
  const int dv = degl[tid];
  if (node < N) dinv[node] = rsqrtf((float)dv + 1.0f);

  // exclusive scan of degl
  pfx[tid] = dv;
  __syncthreads();
  for (int off = 1; off < 256; off <<= 1) {
    int t = (tid >= off) ? pfx[tid - off] : 0;
    __syncthreads();
    pfx[tid] += t;
    __syncthreads();
  }
  const int ex = pfx[tid] - dv;
  if (node < N) rowptr[node] = base + ex;
  curl[tid] = ex;
  __syncthreads();

  if (cnt <= FS_CAP) {
    for (int i = tid; i < cnt; i += 256) {
      int p = csr[base + i];
      int ld = (p >> 17) & 255;
      int pos = atomicAdd(&curl[ld], 1);
      buf[pos] = p & 0x1FFFF;
    }
    __syncthreads();
    for (int i = tid; i < cnt; i += 256) csr[base + i] = buf[i];
  } else {
    curl[tid] = base + ex;
    __syncthreads();
    for (int e = tid; e < E; e += 256) {
      int d = dst[e];
      if ((d >> 8) == b) {
        int pos = atomicAdd(&curl[d & 255], 1);
        csr[pos] = src[e];
      }
    }
  }
}

// ---------------- legacy atomic-scatter fill (fallback when NB > FB_NBMAX) ---

static __global__ void fill_kernel(const int* __restrict__ src, const int* __restrict__ dst,
                                   int* __restrict__ cursor, int* __restrict__ csr, int E) {
  int e = blockIdx.x * blockDim.x + threadIdx.x;
  if (e >= E) return;
  int s = src[e], d = dst[e];
  int pos = atomicAdd(&cursor[d], 1);
  csr[pos] = s;
}

// ---------------- fused propagation step (CSR gather, y-form, fp8) ----------
// cur rows: 40 fp8 bytes padded to 64 B stride -> exactly ONE cache line per edge.
// y' = dinv^2 * (y[row] + sum y[src]);  out += gamma*dinv*(y[row] + sum y[src])
// r2 analysis: all data L3-resident (HBM ~0); kernel is VALU+latency bound.
// This version: packed-f32 accumulate (v_pk_add_f32), 32-bit voffset
// addressing, no NT hint (csr re-read 10x -> keep in L2).

static __global__ __launch_bounds__(256) void gather_kernel(
    const int* __restrict__ rowptr, const int* __restrict__ csr,
    const float* __restrict__ dinv, const float* __restrict__ temp, int k,
    const unsigned char* __restrict__ cur, unsigned char* __restrict__ nxt,
    float4* __restrict__ out, int n5)
{
  int t = blockIdx.x * blockDim.x + threadIdx.x;
  if (t >= n5) return;
  int row = t / 5, c4 = t - row * 5;
  const unsigned c8 = (unsigned)c4 * 8;
  int beg = rowptr[row], end = rowptr[row + 1];
  float dv = dinv[row];

  v2f a0, a1, a2, a3;
  {
    int2 v = *(const int2*)(cur + (((unsigned)row << 6) | c8));   // self term y[row]
    a0 = cvt2lo(v.x); a1 = cvt2hi(v.x);
    a2 = cvt2lo(v.y); a3 = cvt2hi(v.y);
  }

  int e = beg;
  // unroll-8: phase-separated (8 idx loads -> 8 gathers -> packed accumulate)
  for (; e + 7 < end; e += 8) {
    int idx[8];
    #pragma unroll
    for (int j = 0; j < 8; ++j) idx[j] = csr[e + j];
    int2 g[8];
    #pragma unroll
    for (int j = 0; j < 8; ++j) g[j] = *(const int2*)(cur + (((unsigned)idx[j] << 6) | c8));
    #pragma unroll
    for (int j = 0; j < 8; ++j) {
      a0 += cvt2lo(g[j].x); a1 += cvt2hi(g[j].x);
      a2 += cvt2lo(g[j].y); a3 += cvt2hi(g[j].y);
    }
  }
  for (; e + 3 < end; e += 4) {
    int idx[4];
    #pragma unroll
    for (int j = 0; j < 4; ++j) idx[j] = csr[e + j];
    int2 g[4];
    #pragma unroll
    for (int j = 0; j < 4; ++j) g[j] = *(const int2*)(cur + (((unsigned)idx[j] << 6) | c8));
    #pragma unroll
    for (int j = 0; j < 4; ++j) {
      a0 += cvt2lo(g[j].x); a1 += cvt2hi(g[j].x);
      a2 += cvt2lo(g[j].y); a3 += cvt2hi(g[j].y);
    }
  }
  for (; e < end; ++e) {
    int2 g = *(const int2*)(cur + (((unsigned)csr[e] << 6) | c8));
    a0 += cvt2lo(g.x); a1 += cvt2hi(g.x);
    a2 += cvt2lo(g.y); a3 += cvt2hi(g.y);
  }

  float d2 = dv * dv;
  float y[8] = {d2 * a0[0], d2 * a0[1], d2 * a1[0], d2 * a1[1],
                d2 * a2[0], d2 * a2[1], d2 * a3[0], d2 * a3[1]};
  *(int2*)(nxt + (((unsigned)row << 6) | c8)) = pk8f8(y);

  float gd = fmaxf(temp[k], 0.0f) * dv;   // gamma * dinv
  int oi = row * 10 + c4 * 2;
  float4 o0 = out[oi], o1 = out[oi + 1];
  out[oi]     = make_float4(fmaf(gd, a0[0], o0.x), fmaf(gd, a0[1], o0.y),
                            fmaf(gd, a1[0], o0.z), fmaf(gd, a1[1], o0.w));
  out[oi + 1] = make_float4(fmaf(gd, a2[0], o1.x), fmaf(gd, a2[1], o1.y),
                            fmaf(gd, a3[0], o1.z), fmaf(gd, a3[1], o1.w));
}

// ---------------- fallback scatter path (only if ws too small) ----------------

static __global__ void selfloop_kernel(const float* __restrict__ dinv, const float4* __restrict__ cur,
                                       float4* __restrict__ nxt, int n10) {
  int t = blockIdx.x * blockDim.x + threadIdx.x;
  if (t >= n10) return;
  int i = t / 10;
  float dv = dinv[i], s = dv * dv;
  float4 v = cur[t];
  nxt[t] = make_float4(s * v.x, s * v.y, s * v.z, s * v.w);
}

static __global__ void scatter_kernel(const int* __restrict__ src, const int* __restrict__ dst,
                                      const float* __restrict__ dinv,
                                      const float4* __restrict__ cur, float* __restrict__ nxt, int items) {
  int t = blockIdx.x * blockDim.x + threadIdx.x;
  if (t >= items) return;
  int e = t / 10, c4 = t - e * 10;
  int s = src[e], d = dst[e];
  float nm = dinv[s] * dinv[d];
  float4 v = cur[s * 10 + c4];
  float* np = nxt + (size_t)d * NCLS + c4 * 4;
  unsafeAtomicAdd(np + 0, nm * v.x);
  unsafeAtomicAdd(np + 1, nm * v.y);
  unsafeAtomicAdd(np + 2, nm * v.z);
  unsafeAtomicAdd(np + 3, nm * v.w);
}

static __global__ void axpy_kernel(const float* __restrict__ temp, int k,
                                   const float4* __restrict__ nxt, float4* __restrict__ out, int n10) {
  int t = blockIdx.x * blockDim.x + threadIdx.x;
  if (t >= n10) return;
  float g = fmaxf(temp[k], 0.0f);
  float4 v = nxt[t], o = out[t];
  out[t] = make_float4(o.x + g * v.x, o.y + g * v.y, o.z + g * v.z, o.w + g * v.w);
}

static __global__ __launch_bounds__(256) void mlp_kernel(
    const float* __restrict__ x, const float* __restrict__ w1, const float* __restrict__ b1,
    const float* __restrict__ w2, const float* __restrict__ b2, const float* __restrict__ temp,
    float* __restrict__ cur, float* __restrict__ out, int N)
{
  __shared__ __align__(16) float xs[4][NFEAT];
  __shared__ float hs[4][HID];
  const int w = threadIdx.x >> 6, lane = threadIdx.x & 63;
  const int i = blockIdx.x * 4 + w;
  if (i < N) {
    const float4* xrow = (const float4*)(x + (size_t)i * NFEAT);
    float4* xsr = (float4*)xs[w];
    xsr[lane]      = xrow[lane];
    xsr[lane + 64] = xrow[lane + 64];
  }
  __syncthreads();
  if (i < N) {
    float acc = b1[lane];
    #pragma unroll 8
    for (int k = 0; k < NFEAT; ++k)
      acc = fmaf(xs[w][k], w1[k * HID + lane], acc);
    hs[w][lane] = fmaxf(acc, 0.0f);
  }
  __syncthreads();
  if (i < N && lane < NCLS) {
    float a2 = b2[lane];
    #pragma unroll
    for (int j = 0; j < HID; ++j)
      a2 = fmaf(hs[w][j], w2[j * NCLS + lane], a2);
    float g0 = fmaxf(temp[0], 0.0f);
    cur[(size_t)i * NCLS + lane] = a2;
    out[(size_t)i * NCLS + lane] = g0 * a2;
  }
}

// ---------------- log_softmax ----------------
static __global__ void logsoftmax_kernel(float* __restrict__ out, int N) {
  int i = blockIdx.x * blockDim.x + threadIdx.x;
  if (i >= N) return;
  float4* row = (float4*)(out + (size_t)i * NCLS);
  float4 v[10];
  float m = -3.4e38f;
  #pragma unroll
  for (int r = 0; r < 10; ++r) {
    v[r] = row[r];
    m = fmaxf(m, fmaxf(fmaxf(v[r].x, v[r].y), fmaxf(v[r].z, v[r].w)));
  }
  float sum = 0.0f;
  #pragma unroll
  for (int r = 0; r < 10; ++r)
    sum += __expf(v[r].x - m) + __expf(v[r].y - m) + __expf(v[r].z - m) + __expf(v[r].w - m);
  float l = m + __logf(sum);
  #pragma unroll
  for (int r = 0; r < 10; ++r)
    row[r] = make_float4(v[r].x - l, v[r].y - l, v[r].z - l, v[r].w - l);
}

// ---------------- launch ----------------

extern "C" void kernel_launch(void* const* d_in, const int* in_sizes, int n_in,
                              void* d_out, int out_size, void* d_ws, size_t ws_size,
                              hipStream_t stream) {
  const float* x    = (const float*)d_in[0];
  const int*   ei   = (const int*)d_in[1];
  const float* w1   = (const float*)d_in[2];
  const float* b1   = (const float*)d_in[3];
  const float* w2   = (const float*)d_in[4];
  const float* b2   = (const float*)d_in[5];
  const float* temp = (const float*)d_in[6];

  const int N = in_sizes[0] / NFEAT;   // 100000
  const int E = in_sizes[1] / 2;       // 3200000
  const int* src = ei;
  const int* dst = ei + E;
  float* out = (float*)d_out;

  char* ws = (char*)d_ws;
  size_t off = 0;
  auto alloc = [&](size_t bytes) { size_t o = off; off += (bytes + 255) & ~(size_t)255; return o; };
  float* dinv   = (float*)(ws + alloc((size_t)N * 4));
  int*   deg    = (int*)  (ws + alloc((size_t)N * 4));
  unsigned char* curA = (unsigned char*)(ws + alloc((size_t)N * 64));  // fp8, 64 B rows
  unsigned char* curB = (unsigned char*)(ws + alloc((size_t)N * 64));
  int*   rowptr = (int*)  (ws + alloc((size_t)(N + 1) * 4));
  int*   cursor = (int*)  (ws + alloc((size_t)N * 4));
  int*   bsum   = (int*)  (ws + alloc(1024 * 4));
  int*   total  = (int*)  (ws + alloc(256));
  int*   bcnt   = (int*)  (ws + alloc(FB_NBMAX * 4));
  int*   bbase  = (int*)  (ws + alloc(FB_NBMAX * 4));
  int*   bcur   = (int*)  (ws + alloc(FB_NBMAX * 4));
  short* w1bf   = (short*)(ws + alloc((size_t)NFEAT * HID * 2));
  short* w2bf   = (short*)(ws + alloc((size_t)48 * HID * 2));
  int*   csr    = (int*)  (ws + alloc((size_t)E * 4));
  // fallback needs f32 cur buffers
  float* fA     = (float*)curA;
  const bool csr_ok = (off <= ws_size);

  const int NB = (N + 255) >> 8;  // 256-node buckets

  if (csr_ok && NB <= FB_NBMAX && N <= (1 << 17)) {
    // ---- primary path: deg/dinv/rowptr fused into bucketed CSR build ----
    w1conv_kernel<<<(NFEAT * HID + 255) / 256, 256, 0, stream>>>(w1, w1bf, bcnt, FB_NBMAX);
    w2conv_kernel<<<(48 * HID + 255) / 256, 256, 0, stream>>>(w2, w2bf);

    bcount_kernel<<<(E + FB_EPB - 1) / FB_EPB, 256, 0, stream>>>(dst, bcnt, E, NB);
    bscan_kernel<<<1, 512, 0, stream>>>(bcnt, bbase, bcur, rowptr, NB, N, E);
    fill_bin_kernel<<<(E + FB_EPB - 1) / FB_EPB, 256, 0, stream>>>(src, dst, bcur, csr, E, NB);
    fill_scatter2_kernel<<<NB, 256, 0, stream>>>(bbase, bcnt, csr, src, dst, dinv, rowptr, N, E);

    mlp_mfma_kernel<<<(N + 63) / 64, 256, 0, stream>>>(x, w1bf, b1, w2bf, b2, temp, dinv,
                                                       curA, out, N);

    const int n5 = N * 5;
    unsigned char* cur = curA;
    unsigned char* nxt = curB;
    for (int k = 0; k < 10; ++k) {
      gather_kernel<<<(n5 + 255) / 256, 256, 0, stream>>>(
          rowptr, csr, dinv, temp, k + 1, cur, nxt, (float4*)out, n5);
      unsigned char* t2 = cur; cur = nxt; nxt = t2;
    }
    logsoftmax_kernel<<<(N + 255) / 256, 256, 0, stream>>>(out, N);
    return;
  }

  (void)hipMemsetAsync(deg, 0, (size_t)N * sizeof(int), stream);
  deg_i_kernel<<<(E + 255) / 256, 256, 0, stream>>>(dst, deg, E);
  dinv_kernel<<<(N + 255) / 256, 256, 0, stream>>>(deg, dinv, N);

  if (csr_ok) {
    // ---- legacy CSR path (large N): atomic scatter fill ----
    w1conv_kernel<<<(NFEAT * HID + 255) / 256, 256, 0, stream>>>(w1, w1bf, bcnt, FB_NBMAX);
    w2conv_kernel<<<(48 * HID + 255) / 256, 256, 0, stream>>>(w2, w2bf);
    mlp_mfma_kernel<<<(N + 63) / 64, 256, 0, stream>>>(x, w1bf, b1, w2bf, b2, temp, dinv,
                                                       curA, out, N);

    const int nb = (N + 255) / 256;
    scan1_kernel<<<nb, 256, 0, stream>>>(deg, bsum, N);
    scan2_kernel<<<1, 512, 0, stream>>>(bsum, total, nb);
    scan3_kernel<<<(N + 256) / 256, 256, 0, stream>>>(deg, bsum, total, rowptr, cursor, N);
    fill_kernel<<<(E + 255) / 256, 256, 0, stream>>>(src, dst, cursor, csr, E);

    const int n5 = N * 5;
    unsigned char* cur = curA;
    unsigned char* nxt = curB;
    for (int k = 0; k < 10; ++k) {
      gather_kernel<<<(n5 + 255) / 256, 256, 0, stream>>>(
          rowptr, csr, dinv, temp, k + 1, cur, nxt, (float4*)out, n5);
      unsigned char* t2 = cur; cur = nxt; nxt = t2;
    }
  } else {
    // f32 fallback (uses curA region as float storage; requires less ws than main path)
    float* fB = (float*)curB;
    mlp_kernel<<<(N + 3) / 4, 256, 0, stream>>>(x, w1, b1, w2, b2, temp, fA, out, N);
    const int n10 = N * 10;
    const int items = E * 10;
    float* cur = fA;
    float* nxt = fB;
    for (int k = 0; k < 10; ++k) {
      selfloop_kernel<<<(n10 + 255) / 256, 256, 0, stream>>>(dinv, (const float4*)cur, (float4*)nxt, n10);
      scatter_kernel<<<(items + 255) / 256, 256, 0, stream>>>(src, dst, dinv, (const float4*)cur, nxt, items);
      axpy_kernel<<<(n10 + 255) / 256, 256, 0, stream>>>(temp, k + 1, (const float4*)nxt, (float4*)out, n10);
      float* t2 = cur; cur = nxt; nxt = t2;
    }
  }

  logsoftmax_kernel<<<(N + 255) / 256, 256, 0, stream>>>(out, N);
}

// Round 5
// 763.098 us; speedup vs baseline: 1.6391x; 1.0968x over previous
//
#include <hip/hip_runtime.h>
#include <hip/hip_bf16.h>
#include <hip/hip_fp16.h>
#include <hip/hip_fp8.h>

#define NFEAT 512
#define HID   64
#define NCLS  40

typedef short bf16x8 __attribute__((ext_vector_type(8)));
typedef float f32x4  __attribute__((ext_vector_type(4)));
typedef float v2f    __attribute__((ext_vector_type(2)));

__device__ inline short bfs(float f) {
  __hip_bfloat16 h = __float2bfloat16(f);
  return __builtin_bit_cast(short, h);
}
__device__ inline int pk(float a, float b) {  // two bf16 packed, a = low half
  return (int)(unsigned short)bfs(a) | ((int)(unsigned short)bfs(b) << 16);
}

// ---- fp8 e4m3 (OCP) pack/unpack ----
// NOTE: __builtin_amdgcn_cvt_pk_f32_fp8's word-select arg must be a LITERAL
// constant at the call site (frontend-checked before inlining) -> two fns.
__device__ inline v2f cvt2lo(int v) {
#if __has_builtin(__builtin_amdgcn_cvt_pk_f32_fp8)
  return __builtin_amdgcn_cvt_pk_f32_fp8(v, false);
#else
  v2f r; const unsigned char* b = (const unsigned char*)&v;
  __hip_fp8_e4m3 h0; h0.__x = b[0]; r[0] = (float)h0;
  __hip_fp8_e4m3 h1; h1.__x = b[1]; r[1] = (float)h1;
  return r;
#endif
}
__device__ inline v2f cvt2hi(int v) {
#if __has_builtin(__builtin_amdgcn_cvt_pk_f32_fp8)
  return __builtin_amdgcn_cvt_pk_f32_fp8(v, true);
#else
  v2f r; const unsigned char* b = (const unsigned char*)&v;
  __hip_fp8_e4m3 h0; h0.__x = b[2]; r[0] = (float)h0;
  __hip_fp8_e4m3 h1; h1.__x = b[3]; r[1] = (float)h1;
  return r;
#endif
}
__device__ inline int2 pk8f8(const float f[8]) {
#if __has_builtin(__builtin_amdgcn_cvt_pk_fp8_f32)
  int lo = 0, hi = 0;
  lo = __builtin_amdgcn_cvt_pk_fp8_f32(f[0], f[1], lo, false);
  lo = __builtin_amdgcn_cvt_pk_fp8_f32(f[2], f[3], lo, true);
  hi = __builtin_amdgcn_cvt_pk_fp8_f32(f[4], f[5], hi, false);
  hi = __builtin_amdgcn_cvt_pk_fp8_f32(f[6], f[7], hi, true);
  return make_int2(lo, hi);
#else
  int2 r; unsigned char* b = (unsigned char*)&r;
  #pragma unroll
  for (int i = 0; i < 8; ++i) { __hip_fp8_e4m3 h((float)f[i]); b[i] = h.__x; }
  return r;
#endif
}
__device__ inline unsigned char f8b(float v) {
#if __has_builtin(__builtin_amdgcn_cvt_pk_fp8_f32)
  int r = __builtin_amdgcn_cvt_pk_fp8_f32(v, v, 0, false);
  return (unsigned char)(r & 0xff);
#else
  __hip_fp8_e4m3 h(v); return h.__x;
#endif
}

// ---------------- degree / dinv (legacy/fallback paths only) ----------------

static __global__ void deg_i_kernel(const int* __restrict__ dst, int* __restrict__ deg, int E) {
  int e = blockIdx.x * blockDim.x + threadIdx.x;
  if (e < E) atomicAdd(&deg[dst[e]], 1);
}

static __global__ void dinv_kernel(const int* __restrict__ deg, float* __restrict__ dinv, int N) {
  int i = blockIdx.x * blockDim.x + threadIdx.x;
  if (i < N) dinv[i] = rsqrtf((float)deg[i] + 1.0f);
}

// ---------------- weight preconversion to bf16 (+ bcnt zeroing fused) -------
static __global__ void w1conv_kernel(const float* __restrict__ w1, short* __restrict__ w1bf,
                                     int* __restrict__ bcnt, int nbz) {
  int t = blockIdx.x * blockDim.x + threadIdx.x;  // 32768
  if (t < nbz) bcnt[t] = 0;
  if (t >= NFEAT * HID) return;
  int k = t >> 6, n = t & 63;
  w1bf[n * NFEAT + k] = bfs(w1[k * HID + n]);
}
static __global__ void w2conv_kernel(const float* __restrict__ w2, short* __restrict__ w2bf) {
  int t = blockIdx.x * blockDim.x + threadIdx.x;  // 3072
  if (t >= 48 * HID) return;
  int n = t >> 6, k = t & 63;
  w2bf[t] = (n < NCLS) ? bfs(w2[k * NCLS + n]) : (short)0;
}

// ---------------- MFMA MLP ----------------
static __global__ __launch_bounds__(256) void mlp_mfma_kernel(
    const float* __restrict__ x, const short* __restrict__ w1bf, const float* __restrict__ b1,
    const short* __restrict__ w2bf, const float* __restrict__ b2, const float* __restrict__ temp,
    const float* __restrict__ dinv, unsigned char* __restrict__ cur, float* __restrict__ out, int N)
{
  __shared__ __align__(16) short Al[64][72];
  __shared__ __align__(16) short Bl[64][72];
  __shared__ __align__(16) short Hl[64][72];
  __shared__ __align__(16) short W2l[48][72];
  const int tid = threadIdx.x;
  const int w = tid >> 6, lane = tid & 63;
  const int q = lane >> 4, m = lane & 15;
  const long row0 = (long)blockIdx.x * 64;

  if (tid < 192) {
    int n = tid >> 2, ch = tid & 3;
    const int4* sp = (const int4*)(w2bf + n * 64 + ch * 16);
    *(int4*)&W2l[n][ch * 16]     = sp[0];
    *(int4*)&W2l[n][ch * 16 + 8] = sp[1];
  }

  f32x4 zf = {0.f, 0.f, 0.f, 0.f};
  f32x4 acc[4] = {zf, zf, zf, zf};

  const int ar = tid >> 2, ch = tid & 3;
  const long gr = row0 + ar;

  for (int kk = 0; kk < NFEAT; kk += 64) {
    float4 v0, v1, v2, v3;
    if (gr < N) {
      const float4* xp = (const float4*)(x + gr * NFEAT + kk + ch * 16);
      v0 = xp[0]; v1 = xp[1]; v2 = xp[2]; v3 = xp[3];
    } else {
      v0 = v1 = v2 = v3 = make_float4(0.f, 0.f, 0.f, 0.f);
    }
    const int4* bp = (const int4*)(w1bf + ar * NFEAT + kk + ch * 16);
    int4 bv0 = bp[0], bv1 = bp[1];

    __syncthreads();
    int4 a0 = make_int4(pk(v0.x, v0.y), pk(v0.z, v0.w), pk(v1.x, v1.y), pk(v1.z, v1.w));
    int4 a1 = make_int4(pk(v2.x, v2.y), pk(v2.z, v2.w), pk(v3.x, v3.y), pk(v3.z, v3.w));
    *(int4*)&Al[ar][ch * 16]     = a0;
    *(int4*)&Al[ar][ch * 16 + 8] = a1;
    *(int4*)&Bl[ar][ch * 16]     = bv0;
    *(int4*)&Bl[ar][ch * 16 + 8] = bv1;
    __syncthreads();

    #pragma unroll
    for (int s = 0; s < 2; ++s) {
      bf16x8 a = *(const bf16x8*)&Al[w * 16 + m][s * 32 + q * 8];
      #pragma unroll
      for (int c = 0; c < 4; ++c) {
        bf16x8 b = *(const bf16x8*)&Bl[c * 16 + m][s * 32 + q * 8];
        acc[c] = __builtin_amdgcn_mfma_f32_16x16x32_bf16(a, b, acc[c], 0, 0, 0);
      }
    }
  }

  #pragma unroll
  for (int c = 0; c < 4; ++c) {
    int col = c * 16 + m;
    float bb = b1[col];
    #pragma unroll
    for (int r = 0; r < 4; ++r) {
      int rl = w * 16 + q * 4 + r;
      Hl[rl][col] = bfs(fmaxf(acc[c][r] + bb, 0.0f));
    }
  }
  __syncthreads();

  f32x4 acc2[3] = {zf, zf, zf};
  #pragma unroll
  for (int s = 0; s < 2; ++s) {
    bf16x8 a = *(const bf16x8*)&Hl[w * 16 + m][s * 32 + q * 8];
    #pragma unroll
    for (int c = 0; c < 3; ++c) {
      bf16x8 b = *(const bf16x8*)&W2l[c * 16 + m][s * 32 + q * 8];
      acc2[c] = __builtin_amdgcn_mfma_f32_16x16x32_bf16(a, b, acc2[c], 0, 0, 0);
    }
  }

  float g0 = fmaxf(temp[0], 0.0f);
  #pragma unroll
  for (int c = 0; c < 3; ++c) {
    int col = c * 16 + m;
    if (col < NCLS) {
      float bb = b2[col];
      #pragma unroll
      for (int r = 0; r < 4; ++r) {
        long grow = row0 + w * 16 + q * 4 + r;
        if (grow < N) {
          float vv = acc2[c][r] + bb;
          cur[grow * 64 + col] = f8b(dinv[grow] * vv);  // y0 = dinv*h, fp8
          out[grow * NCLS + col] = g0 * vv;
        }
      }
    }
  }
}

// ---------------- legacy scan kernels (fallback paths only) ----------------

static __global__ __launch_bounds__(256) void scan1_kernel(const int* __restrict__ deg,
                                                           int* __restrict__ bsum, int N) {
  __shared__ int s[256];
  int tid = threadIdx.x;
  int i = blockIdx.x * 256 + tid;
  s[tid] = (i < N) ? deg[i] : 0;
  __syncthreads();
  for (int off = 128; off > 0; off >>= 1) {
    if (tid < off) s[tid] += s[tid + off];
    __syncthreads();
  }
  if (tid == 0) bsum[blockIdx.x] = s[0];
}

static __global__ __launch_bounds__(512) void scan2_kernel(int* __restrict__ bsum,
                                                           int* __restrict__ total, int nb) {
  __shared__ int s[512];
  int tid = threadIdx.x;
  int v = (tid < nb) ? bsum[tid] : 0;
  s[tid] = v;
  __syncthreads();
  for (int off = 1; off < 512; off <<= 1) {
    int t = (tid >= off) ? s[tid - off] : 0;
    __syncthreads();
    s[tid] += t;
    __syncthreads();
  }
  if (tid < nb) bsum[tid] = s[tid] - v;
  if (tid == 511) *total = s[511];
}

static __global__ __launch_bounds__(256) void scan3_kernel(const int* __restrict__ deg,
                                                           const int* __restrict__ bsum,
                                                           const int* __restrict__ total,
                                                           int* __restrict__ rowptr,
                                                           int* __restrict__ cursor, int N) {
  __shared__ int s[256];
  int tid = threadIdx.x;
  int i = blockIdx.x * 256 + tid;
  int v = (i < N) ? deg[i] : 0;
  s[tid] = v;
  __syncthreads();
  for (int off = 1; off < 256; off <<= 1) {
    int t = (tid >= off) ? s[tid - off] : 0;
    __syncthreads();
    s[tid] += t;
    __syncthreads();
  }
  if (i < N) {
    int e = bsum[blockIdx.x] + s[tid] - v;
    rowptr[i] = e;
    cursor[i] = e;
  }
  if (i == N) rowptr[N] = *total;
}

// ---------------- CSR build: bucketed counting sort (deg/dinv/rowptr fused) --

#define FB_EPT 16
#define FB_EPB (256 * FB_EPT)   // 4096 edges/block
#define FB_NBMAX 512            // supports N <= 131072
#define FS_CAP 12288            // bucket capacity (uniform input: ~8200 +- 90)

static __global__ __launch_bounds__(256) void bcount_kernel(
    const int* __restrict__ dst, int* __restrict__ bcnt, int E, int NB)
{
  __shared__ int cnt[FB_NBMAX];
  const int tid = threadIdx.x;
  cnt[tid] = 0; cnt[tid + 256] = 0;
  __syncthreads();
  const int e0 = blockIdx.x * FB_EPB;
  #pragma unroll
  for (int j = 0; j < FB_EPT; ++j) {
    int e = e0 + j * 256 + tid;
    if (e < E) atomicAdd(&cnt[dst[e] >> 8], 1);
  }
  __syncthreads();
  int b0 = tid, b1 = tid + 256;
  if (b0 < NB && cnt[b0]) atomicAdd(&bcnt[b0], cnt[b0]);
  if (b1 < NB && cnt[b1]) atomicAdd(&bcnt[b1], cnt[b1]);
}

static __global__ __launch_bounds__(512) void bscan_kernel(
    const int* __restrict__ bcnt, int* __restrict__ bbase, int* __restrict__ bcur,
    int* __restrict__ rowptr, int NB, int N, int E)
{
  __shared__ int s[512];
  int tid = threadIdx.x;
  int v = (tid < NB) ? bcnt[tid] : 0;
  s[tid] = v;
  __syncthreads();
  for (int off = 1; off < 512; off <<= 1) {
    int t = (tid >= off) ? s[tid - off] : 0;
    __syncthreads();
    s[tid] += t;
    __syncthreads();
  }
  if (tid < NB) { int ex = s[tid] - v; bbase[tid] = ex; bcur[tid] = ex; }
  if (tid == 0) rowptr[N] = E;
}

static __global__ __launch_bounds__(256) void fill_bin_kernel(
    const int* __restrict__ src, const int* __restrict__ dst,
    int* __restrict__ bcur, int* __restrict__ csr, int E, int NB)
{
  __shared__ int cnt[FB_NBMAX];
  __shared__ int pfx[FB_NBMAX];
  __shared__ int gbase[FB_NBMAX];
  __shared__ int stg[FB_EPB];
  __shared__ unsigned short bmap[FB_EPB];
  const int tid = threadIdx.x;
  const int e0 = blockIdx.x * FB_EPB;

  cnt[tid] = 0; cnt[tid + 256] = 0;
  __syncthreads();

  int pk_[FB_EPT], b_[FB_EPT], r_[FB_EPT];
  #pragma unroll
  for (int j = 0; j < FB_EPT; ++j) {
    int e = e0 + j * 256 + tid;  // coalesced
    if (e < E) {
      int s = src[e], d = dst[e];
      pk_[j] = s | ((d & 255) << 17);
      b_[j] = d >> 8;
      r_[j] = atomicAdd(&cnt[b_[j]], 1);
    } else b_[j] = -1;
  }
  __syncthreads();

  // inclusive Hillis-Steele scan of cnt into pfx (512 entries, 2/thread)
  pfx[tid] = cnt[tid]; pfx[tid + 256] = cnt[tid + 256];
  __syncthreads();
  for (int off = 1; off < FB_NBMAX; off <<= 1) {
    int a = (tid >= off) ? pfx[tid - off] : 0;
    int b = (tid + 256 >= off) ? pfx[tid + 256 - off] : 0;
    __syncthreads();
    pfx[tid] += a; pfx[tid + 256] += b;
    __syncthreads();
  }

  // reserve global space: one atomic per non-empty bucket
  {
    int b0 = tid, b1 = tid + 256;
    if (b0 < NB && cnt[b0]) gbase[b0] = atomicAdd(&bcur[b0], cnt[b0]);
    if (b1 < NB && cnt[b1]) gbase[b1] = atomicAdd(&bcur[b1], cnt[b1]);
  }
  __syncthreads();

  // place into LDS staging grouped by bucket
  #pragma unroll
  for (int j = 0; j < FB_EPT; ++j) {
    if (b_[j] >= 0) {
      int slot = pfx[b_[j]] - cnt[b_[j]] + r_[j];
      stg[slot] = pk_[j];
      bmap[slot] = (unsigned short)b_[j];
    }
  }
  __syncthreads();

  // copy out: consecutive slots -> consecutive global addresses within a run
  const int total = pfx[FB_NBMAX - 1];
  for (int slot = tid; slot < total; slot += 256) {
    int b = bmap[slot];
    int local = slot - (pfx[b] - cnt[b]);
    csr[gbase[b] + local] = stg[slot];
  }
}

static __global__ __launch_bounds__(256) void fill_scatter2_kernel(
    const int* __restrict__ bbase_a, const int* __restrict__ bcnt,
    int* __restrict__ csr, const int* __restrict__ src, const int* __restrict__ dst,
    float* __restrict__ dinv, int* __restrict__ rowptr, int N, int E)
{
  __shared__ int degl[256];
  __shared__ int pfx[256];
  __shared__ int curl[256];
  __shared__ int buf[FS_CAP];
  const int tid = threadIdx.x;
  const int b = blockIdx.x;
  const int base = bbase_a[b], cnt = bcnt[b];
  const int node = (b << 8) + tid;

  degl[tid] = 0;
  __syncthreads();
  if (cnt <= FS_CAP) {
    for (int i = tid; i < cnt; i += 256) {
      int p = csr[base + i];
      atomicAdd(&degl[(p >> 17) & 255], 1);
    }
  } else {
    // overflow safety net (P~0): recount from raw edge list
    for (int e = tid; e < E; e += 256) {
      int d = dst[e];
      if ((d >> 8) == b) atomicAdd(&degl[d & 255], 1);
    }
  }
  __syncthreads();
  const int dv = degl[tid];
  if (node < N) dinv[node] = rsqrtf((float)dv + 1.0f);

  // exclusive scan of degl
  pfx[tid] = dv;
  __syncthreads();
  for (int off = 1; off < 256; off <<= 1) {
    int t = (tid >= off) ? pfx[tid - off] : 0;
    __syncthreads();
    pfx[tid] += t;
    __syncthreads();
  }
  const int ex = pfx[tid] - dv;
  if (node < N) rowptr[node] = base + ex;
  curl[tid] = ex;
  __syncthreads();

  if (cnt <= FS_CAP) {
    for (int i = tid; i < cnt; i += 256) {
      int p = csr[base + i];
      int ld = (p >> 17) & 255;
      int pos = atomicAdd(&curl[ld], 1);
      buf[pos] = p & 0x1FFFF;
    }
    __syncthreads();
    for (int i = tid; i < cnt; i += 256) csr[base + i] = buf[i];
  } else {
    curl[tid] = base + ex;
    __syncthreads();
    for (int e = tid; e < E; e += 256) {
      int d = dst[e];
      if ((d >> 8) == b) {
        int pos = atomicAdd(&curl[d & 255], 1);
        csr[pos] = src[e];
      }
    }
  }
}

// ---------------- legacy atomic-scatter fill (fallback when NB > FB_NBMAX) ---

static __global__ void fill_kernel(const int* __restrict__ src, const int* __restrict__ dst,
                                   int* __restrict__ cursor, int* __restrict__ csr, int E) {
  int e = blockIdx.x * blockDim.x + threadIdx.x;
  if (e >= E) return;
  int s = src[e], d = dst[e];
  int pos = atomicAdd(&cursor[d], 1);
  csr[pos] = s;
}

// ---------------- fused propagation step (CSR gather, y-form, fp8) ----------
// cur rows: 40 fp8 bytes padded to 64 B stride -> exactly ONE cache line per edge.
// y' = dinv^2 * (y[row] + sum y[src]);  out += gamma*dinv*(y[row] + sum y[src])
// r4 analysis: NOT VALU-bound (~2.5M wave-inst/step ~= 2 us of 55). The cost is
// the serial idx-load-wait -> gather-wait chain, and 5x-redundant csr reads
// (5 chunk-threads/row each load the same idx list). Fix: block-cooperative
// LDS staging of the block's contiguous csr slice (51 rows, coalesced, 1x
// traffic) -> inner loop reads idx from LDS, only the gather VMEM wait remains.

#define GR_ROWS 51
#define GR_CAP  2560   // ints; expected slice ~1632 +- 40 (23 sigma headroom)

template <bool INLDS>
__device__ inline void gather_row(
    const int* __restrict__ ip, int beg, int end, unsigned c8,
    const unsigned char* __restrict__ cur,
    v2f& a0, v2f& a1, v2f& a2, v2f& a3)
{
  int e = beg;
  for (; e + 7 < end; e += 8) {
    int idx[8];
    #pragma unroll
    for (int j = 0; j < 8; ++j) idx[j] = ip[e + j];
    int2 g[8];
    #pragma unroll
    for (int j = 0; j < 8; ++j) g[j] = *(const int2*)(cur + (((unsigned)idx[j] << 6) | c8));
    #pragma unroll
    for (int j = 0; j < 8; ++j) {
      a0 += cvt2lo(g[j].x); a1 += cvt2hi(g[j].x);
      a2 += cvt2lo(g[j].y); a3 += cvt2hi(g[j].y);
    }
  }
  for (; e + 3 < end; e += 4) {
    int idx[4];
    #pragma unroll
    for (int j = 0; j < 4; ++j) idx[j] = ip[e + j];
    int2 g[4];
    #pragma unroll
    for (int j = 0; j < 4; ++j) g[j] = *(const int2*)(cur + (((unsigned)idx[j] << 6) | c8));
    #pragma unroll
    for (int j = 0; j < 4; ++j) {
      a0 += cvt2lo(g[j].x); a1 += cvt2hi(g[j].x);
      a2 += cvt2lo(g[j].y); a3 += cvt2hi(g[j].y);
    }
  }
  for (; e < end; ++e) {
    int2 g = *(const int2*)(cur + (((unsigned)ip[e] << 6) | c8));
    a0 += cvt2lo(g.x); a1 += cvt2hi(g.x);
    a2 += cvt2lo(g.y); a3 += cvt2hi(g.y);
  }
}

static __global__ __launch_bounds__(256) void gather_kernel(
    const int* __restrict__ rowptr, const int* __restrict__ csr,
    const float* __restrict__ dinv, const float* __restrict__ temp, int k,
    const unsigned char* __restrict__ cur, unsigned char* __restrict__ nxt,
    float4* __restrict__ out, int N)
{
  __shared__ int rp[GR_ROWS + 1];
  __shared__ int lidx[GR_CAP];
  const int tid = threadIdx.x;
  const int row0 = blockIdx.x * GR_ROWS;
  const int nrows = min(GR_ROWS, N - row0);

  if (tid <= nrows) rp[tid] = rowptr[row0 + tid];
  __syncthreads();
  const int beg0 = rp[0];
  const int count = rp[nrows] - beg0;
  const bool inlds = (count <= GR_CAP);
  if (inlds) {
    for (int i = tid; i < count; i += 256) lidx[i] = csr[beg0 + i];
  }
  __syncthreads();

  const int r = tid / 5, c4 = tid - r * 5;
  if (r >= nrows) return;
  const int row = row0 + r;
  const unsigned c8 = (unsigned)c4 * 8;
  const float dv = dinv[row];

  v2f a0, a1, a2, a3;
  {
    int2 v = *(const int2*)(cur + (((unsigned)row << 6) | c8));   // self term y[row]
    a0 = cvt2lo(v.x); a1 = cvt2hi(v.x);
    a2 = cvt2lo(v.y); a3 = cvt2hi(v.y);
  }

  if (inlds) {
    gather_row<true>(lidx, rp[r] - beg0, rp[r + 1] - beg0, c8, cur, a0, a1, a2, a3);
  } else {
    gather_row<false>(csr, rp[r], rp[r + 1], c8, cur, a0, a1, a2, a3);
  }

  float d2 = dv * dv;
  float y[8] = {d2 * a0[0], d2 * a0[1], d2 * a1[0], d2 * a1[1],
                d2 * a2[0], d2 * a2[1], d2 * a3[0], d2 * a3[1]};
  *(int2*)(nxt + (((unsigned)row << 6) | c8)) = pk8f8(y);

  float gd = fmaxf(temp[k], 0.0f) * dv;   // gamma * dinv
  int oi = row * 10 + c4 * 2;
  float4 o0 = out[oi], o1 = out[oi + 1];
  out[oi]     = make_float4(fmaf(gd, a0[0], o0.x), fmaf(gd, a0[1], o0.y),
                            fmaf(gd, a1[0], o0.z), fmaf(gd, a1[1], o0.w));
  out[oi + 1] = make_float4(fmaf(gd, a2[0], o1.x), fmaf(gd, a2[1], o1.y),
                            fmaf(gd, a3[0], o1.z), fmaf(gd, a3[1], o1.w));
}

// ---------------- fallback scatter path (only if ws too small) ----------------

static __global__ void selfloop_kernel(const float* __restrict__ dinv, const float4* __restrict__ cur,
                                       float4* __restrict__ nxt, int n10) {
  int t = blockIdx.x * blockDim.x + threadIdx.x;
  if (t >= n10) return;
  int i = t / 10;
  float dv = dinv[i], s = dv * dv;
  float4 v = cur[t];
  nxt[t] = make_float4(s * v.x, s * v.y, s * v.z, s * v.w);
}

static __global__ void scatter_kernel(const int* __restrict__ src, const int* __restrict__ dst,
                                      const float* __restrict__ dinv,
                                      const float4* __restrict__ cur, float* __restrict__ nxt, int items) {
  int t = blockIdx.x * blockDim.x + threadIdx.x;
  if (t >= items) return;
  int e = t / 10, c4 = t - e * 10;
  int s = src[e], d = dst[e];
  float nm = dinv[s] * dinv[d];
  float4 v = cur[s * 10 + c4];
  float* np = nxt + (size_t)d * NCLS + c4 * 4;
  unsafeAtomicAdd(np + 0, nm * v.x);
  unsafeAtomicAdd(np + 1, nm * v.y);
  unsafeAtomicAdd(np + 2, nm * v.z);
  unsafeAtomicAdd(np + 3, nm * v.w);
}

static __global__ void axpy_kernel(const float* __restrict__ temp, int k,
                                   const float4* __restrict__ nxt, float4* __restrict__ out, int n10) {
  int t = blockIdx.x * blockDim.x + threadIdx.x;
  if (t >= n10) return;
  float g = fmaxf(temp[k], 0.0f);
  float4 v = nxt[t], o = out[t];
  out[t] = make_float4(o.x + g * v.x, o.y + g * v.y, o.z + g * v.z, o.w + g * v.w);
}

static __global__ __launch_bounds__(256) void mlp_kernel(
    const float* __restrict__ x, const float* __restrict__ w1, const float* __restrict__ b1,
    const float* __restrict__ w2, const float* __restrict__ b2, const float* __restrict__ temp,
    float* __restrict__ cur, float* __restrict__ out, int N)
{
  __shared__ __align__(16) float xs[4][NFEAT];
  __shared__ float hs[4][HID];
  const int w = threadIdx.x >> 6, lane = threadIdx.x & 63;
  const int i = blockIdx.x * 4 + w;
  if (i < N) {
    const float4* xrow = (const float4*)(x + (size_t)i * NFEAT);
    float4* xsr = (float4*)xs[w];
    xsr[lane]      = xrow[lane];
    xsr[lane + 64] = xrow[lane + 64];
  }
  __syncthreads();
  if (i < N) {
    float acc = b1[lane];
    #pragma unroll 8
    for (int k = 0; k < NFEAT; ++k)
      acc = fmaf(xs[w][k], w1[k * HID + lane], acc);
    hs[w][lane] = fmaxf(acc, 0.0f);
  }
  __syncthreads();
  if (i < N && lane < NCLS) {
    float a2 = b2[lane];
    #pragma unroll
    for (int j = 0; j < HID; ++j)
      a2 = fmaf(hs[w][j], w2[j * NCLS + lane], a2);
    float g0 = fmaxf(temp[0], 0.0f);
    cur[(size_t)i * NCLS + lane] = a2;
    out[(size_t)i * NCLS + lane] = g0 * a2;
  }
}

// ---------------- log_softmax ----------------
static __global__ void logsoftmax_kernel(float* __restrict__ out, int N) {
  int i = blockIdx.x * blockDim.x + threadIdx.x;
  if (i >= N) return;
  float4* row = (float4*)(out + (size_t)i * NCLS);
  float4 v[10];
  float m = -3.4e38f;
  #pragma unroll
  for (int r = 0; r < 10; ++r) {
    v[r] = row[r];
    m = fmaxf(m, fmaxf(fmaxf(v[r].x, v[r].y), fmaxf(v[r].z, v[r].w)));
  }
  float sum = 0.0f;
  #pragma unroll
  for (int r = 0; r < 10; ++r)
    sum += __expf(v[r].x - m) + __expf(v[r].y - m) + __expf(v[r].z - m) + __expf(v[r].w - m);
  float l = m + __logf(sum);
  #pragma unroll
  for (int r = 0; r < 10; ++r)
    row[r] = make_float4(v[r].x - l, v[r].y - l, v[r].z - l, v[r].w - l);
}

// ---------------- launch ----------------

extern "C" void kernel_launch(void* const* d_in, const int* in_sizes, int n_in,
                              void* d_out, int out_size, void* d_ws, size_t ws_size,
                              hipStream_t stream) {
  const float* x    = (const float*)d_in[0];
  const int*   ei   = (const int*)d_in[1];
  const float* w1   = (const float*)d_in[2];
  const float* b1   = (const float*)d_in[3];
  const float* w2   = (const float*)d_in[4];
  const float* b2   = (const float*)d_in[5];
  const float* temp = (const float*)d_in[6];

  const int N = in_sizes[0] / NFEAT;   // 100000
  const int E = in_sizes[1] / 2;       // 3200000
  const int* src = ei;
  const int* dst = ei + E;
  float* out = (float*)d_out;

  char* ws = (char*)d_ws;
  size_t off = 0;
  auto alloc = [&](size_t bytes) { size_t o = off; off += (bytes + 255) & ~(size_t)255; return o; };
  float* dinv   = (float*)(ws + alloc((size_t)N * 4));
  int*   deg    = (int*)  (ws + alloc((size_t)N * 4));
  unsigned char* curA = (unsigned char*)(ws + alloc((size_t)N * 64));  // fp8, 64 B rows
  unsigned char* curB = (unsigned char*)(ws + alloc((size_t)N * 64));
  int*   rowptr = (int*)  (ws + alloc((size_t)(N + 1) * 4));
  int*   cursor = (int*)  (ws + alloc((size_t)N * 4));
  int*   bsum   = (int*)  (ws + alloc(1024 * 4));
  int*   total  = (int*)  (ws + alloc(256));
  int*   bcnt   = (int*)  (ws + alloc(FB_NBMAX * 4));
  int*   bbase  = (int*)  (ws + alloc(FB_NBMAX * 4));
  int*   bcur   = (int*)  (ws + alloc(FB_NBMAX * 4));
  short* w1bf   = (short*)(ws + alloc((size_t)NFEAT * HID * 2));
  short* w2bf   = (short*)(ws + alloc((size_t)48 * HID * 2));
  int*   csr    = (int*)  (ws + alloc((size_t)E * 4));
  // fallback needs f32 cur buffers
  float* fA     = (float*)curA;
  const bool csr_ok = (off <= ws_size);

  const int NB = (N + 255) >> 8;  // 256-node buckets
  const int gblocks = (N + GR_ROWS - 1) / GR_ROWS;

  if (csr_ok && NB <= FB_NBMAX && N <= (1 << 17)) {
    // ---- primary path: deg/dinv/rowptr fused into bucketed CSR build ----
    w1conv_kernel<<<(NFEAT * HID + 255) / 256, 256, 0, stream>>>(w1, w1bf, bcnt, FB_NBMAX);
    w2conv_kernel<<<(48 * HID + 255) / 256, 256, 0, stream>>>(w2, w2bf);

    bcount_kernel<<<(E + FB_EPB - 1) / FB_EPB, 256, 0, stream>>>(dst, bcnt, E, NB);
    bscan_kernel<<<1, 512, 0, stream>>>(bcnt, bbase, bcur, rowptr, NB, N, E);
    fill_bin_kernel<<<(E + FB_EPB - 1) / FB_EPB, 256, 0, stream>>>(src, dst, bcur, csr, E, NB);
    fill_scatter2_kernel<<<NB, 256, 0, stream>>>(bbase, bcnt, csr, src, dst, dinv, rowptr, N, E);

    mlp_mfma_kernel<<<(N + 63) / 64, 256, 0, stream>>>(x, w1bf, b1, w2bf, b2, temp, dinv,
                                                       curA, out, N);

    unsigned char* cur = curA;
    unsigned char* nxt = curB;
    for (int k = 0; k < 10; ++k) {
      gather_kernel<<<gblocks, 256, 0, stream>>>(
          rowptr, csr, dinv, temp, k + 1, cur, nxt, (float4*)out, N);
      unsigned char* t2 = cur; cur = nxt; nxt = t2;
    }
    logsoftmax_kernel<<<(N + 255) / 256, 256, 0, stream>>>(out, N);
    return;
  }

  (void)hipMemsetAsync(deg, 0, (size_t)N * sizeof(int), stream);
  deg_i_kernel<<<(E + 255) / 256, 256, 0, stream>>>(dst, deg, E);
  dinv_kernel<<<(N + 255) / 256, 256, 0, stream>>>(deg, dinv, N);

  if (csr_ok) {
    // ---- legacy CSR path (large N): atomic scatter fill ----
    w1conv_kernel<<<(NFEAT * HID + 255) / 256, 256, 0, stream>>>(w1, w1bf, bcnt, FB_NBMAX);
    w2conv_kernel<<<(48 * HID + 255) / 256, 256, 0, stream>>>(w2, w2bf);
    mlp_mfma_kernel<<<(N + 63) / 64, 256, 0, stream>>>(x, w1bf, b1, w2bf, b2, temp, dinv,
                                                       curA, out, N);

    const int nb = (N + 255) / 256;
    scan1_kernel<<<nb, 256, 0, stream>>>(deg, bsum, N);
    scan2_kernel<<<1, 512, 0, stream>>>(bsum, total, nb);
    scan3_kernel<<<(N + 256) / 256, 256, 0, stream>>>(deg, bsum, total, rowptr, cursor, N);
    fill_kernel<<<(E + 255) / 256, 256, 0, stream>>>(src, dst, cursor, csr, E);

    unsigned char* cur = curA;
    unsigned char* nxt = curB;
    for (int k = 0; k < 10; ++k) {
      gather_kernel<<<gblocks, 256, 0, stream>>>(
          rowptr, csr, dinv, temp, k + 1, cur, nxt, (float4*)out, N);
      unsigned char* t2 = cur; cur = nxt; nxt = t2;
    }
  } else {
    // f32 fallback (uses curA region as float storage; requires less ws than main path)
    float* fB = (float*)curB;
    mlp_kernel<<<(N + 3) / 4, 256, 0, stream>>>(x, w1, b1, w2, b2, temp, fA, out, N);
    const int n10 = N * 10;
    const int items = E * 10;
    float* cur = fA;
    float* nxt = fB;
    for (int k = 0; k < 10; ++k) {
      selfloop_kernel<<<(n10 + 255) / 256, 256, 0, stream>>>(dinv, (const float4*)cur, (float4*)nxt, n10);
      scatter_kernel<<<(items + 255) / 256, 256, 0, stream>>>(src, dst, dinv, (const float4*)cur, nxt, items);
      axpy_kernel<<<(n10 + 255) / 256, 256, 0, stream>>>(temp, k + 1, (const float4*)nxt, (float4*)out, n10);
      float* t2 = cur; cur = nxt; nxt = t2;
    }
  }

  logsoftmax_kernel<<<(N + 255) / 256, 256, 0, stream>>>(out, N);
}